// Round 11
// baseline (393.251 us; speedup 1.0000x reference)
//
#include <hip/hip_runtime.h>

typedef _Float16 f16;
typedef _Float16 f16x4 __attribute__((ext_vector_type(4)));
typedef _Float16 f16x8 __attribute__((ext_vector_type(8)));
typedef float f32x4 __attribute__((ext_vector_type(4)));

#define DM 2048
#define NT 4096
#define SEQ 2048
#define HD 128
#define NBH 32
// 1/sqrt(128) * log2(e): scores come out in log2 domain -> exp2 is one v_exp_f32
#define QSCALE (0.08838834764831845f * 1.4426950408889634f)

__device__ __forceinline__ void gload16(const f16* g, f16* l) {
  __builtin_amdgcn_global_load_lds(
      (const __attribute__((address_space(1))) void*)g,
      (__attribute__((address_space(3))) void*)l, 16, 0, 0);
}

#define LGKM0                                        \
  asm volatile("s_waitcnt lgkmcnt(0)" ::: "memory"); \
  __builtin_amdgcn_sched_barrier(0)
#define VMC6                                       \
  asm volatile("s_waitcnt vmcnt(6)" ::: "memory"); \
  __builtin_amdgcn_sched_barrier(0)
#define VMC4                                       \
  asm volatile("s_waitcnt vmcnt(4)" ::: "memory"); \
  __builtin_amdgcn_sched_barrier(0)
#define VMC0                                       \
  asm volatile("s_waitcnt vmcnt(0)" ::: "memory"); \
  __builtin_amdgcn_sched_barrier(0)

__global__ __launch_bounds__(256) void cvt_f32_f16(const float* __restrict__ src,
                                                   f16* __restrict__ dst, int n4) {
  int i = blockIdx.x * 256 + threadIdx.x;
  int st = gridDim.x * 256;
  for (; i < n4; i += st) {
    float4 v = ((const float4*)src)[i];
    f16x4 h = {(f16)v.x, (f16)v.y, (f16)v.z, (f16)v.w};
    ((f16x4*)dst)[i] = h;
  }
}

// merged convert: hs (2*2^20 f32x4) -> hsd, Wq/Wk/Wv -> wd concat, Wo -> wod
// (Wo region only processed when n4 == 6M; else caller converts Wo separately)
__global__ __launch_bounds__(256) void cvt5_f32_f16(
    const float* __restrict__ hs, const float* __restrict__ s0,
    const float* __restrict__ s1, const float* __restrict__ s2,
    const float* __restrict__ s3, f16* __restrict__ hsd, f16* __restrict__ wd,
    f16* __restrict__ wod, int n4) {
  int i = blockIdx.x * 256 + threadIdx.x;
  int st = gridDim.x * 256;
  for (; i < n4; i += st) {
    float4 v;
    f16x4 h;
    if (i < 2 * 1048576) {
      v = ((const float4*)hs)[i];
      h[0] = (f16)v.x; h[1] = (f16)v.y; h[2] = (f16)v.z; h[3] = (f16)v.w;
      ((f16x4*)hsd)[i] = h;
    } else {
      const int j = i - 2 * 1048576;
      const int r = j >> 20, jj = j & 1048575;
      const float* s = (r == 0) ? s0 : ((r == 1) ? s1 : ((r == 2) ? s2 : s3));
      v = ((const float4*)s)[jj];
      h[0] = (f16)v.x; h[1] = (f16)v.y; h[2] = (f16)v.z; h[3] = (f16)v.w;
      if (r < 3) ((f16x4*)wd)[j] = h;
      else ((f16x4*)wod)[jj] = h;
    }
  }
}

// ============================================================================
// 8-phase-style GEMM: C = A(4096x2048) * B^T, B row-major [N][2048].
// Tile BM=128 x BN=256, BK=64, 8 waves (2M x 4N), wave tile 64x64.
// Triple-buffered LDS, 2-ahead staging, counted vmcnt(6), XOR swizzle, setprio.
// ============================================================================
template <int MODE>
__global__ __launch_bounds__(512, 2) void gemm8(const f16* __restrict__ A,
                                                const f16* __restrict__ Bm,
                                                const float* __restrict__ bias1,
                                                const float* __restrict__ bias2,
                                                float* __restrict__ outF,
                                                f16* __restrict__ outQ,
                                                f16* __restrict__ outK,
                                                f16* __restrict__ outV) {
  __shared__ __align__(16) f16 smem[73728];  // 144 KiB -> 1 block/CU, 8 waves
  const int tid = threadIdx.x;
  const int w = tid >> 6, l = tid & 63;
  const int wr = w >> 2, wc = w & 3;  // 2M x 4N wave grid
  const int sl = l & 15, t4 = l >> 4;

  const int nbx = gridDim.x, nby = gridDim.y;
  const int flat = blockIdx.y * nbx + blockIdx.x;
  const int chunk = (nbx * nby) >> 3;
  const int swz = (flat & 7) * chunk + (flat >> 3);
  const int col0 = (swz / nby) * 256, row0 = (swz % nby) * 128;

  f32x4 acc[4][4] = {};

  const int sr8 = l >> 3;
  const int sch = (l & 7) ^ (sr8 & 7);
  const f16* gA0 = A + (size_t)(row0 + w * 8 + sr8) * DM + sch * 8;
  const f16* gB0 = Bm + (size_t)(col0 + w * 8 + sr8) * DM + sch * 8;

#define SA(tb, kt, r) \
  gload16(gA0 + (size_t)(r) * 64 * DM + (kt) * 64, smem + (tb) * 8192 + (r) * 4096 + w * 512)
#define SB(tb, kt, r)                               \
  gload16(gB0 + (size_t)(r) * 64 * DM + (kt) * 64, \
          smem + 24576 + (tb) * 16384 + (r) * 4096 + w * 512)
#define MF(mi, ni, av, bv) \
  acc[mi][ni] = __builtin_amdgcn_mfma_f32_16x16x32_f16(av, bv, acc[mi][ni], 0, 0, 0)

  const int sx = sl & 7;
  const int sk0 = (t4 ^ sx) * 8;
  const int sk1 = ((4 + t4) ^ sx) * 8;
  const int arow = (wr * 64 + sl) * 64;
  const int brow = (wc * 64 + sl) * 64;

  SA(0, 0, 0); SA(0, 0, 1);
  SB(0, 0, 0); SB(0, 0, 1); SB(0, 0, 2); SB(0, 0, 3);
  SA(1, 1, 0); SA(1, 1, 1);
  SB(1, 1, 0); SB(1, 1, 1); SB(1, 1, 2); SB(1, 1, 3);
  VMC6;
  __builtin_amdgcn_s_barrier();

  int cur = 0;
#pragma unroll 1
  for (int t = 0; t < 32; ++t) {
    const int nb = (cur == 0) ? 2 : cur - 1;
    const bool pf = (t + 2 < 32);
    const int ab = cur * 8192;
    const int bb = 24576 + cur * 16384;
    f16x8 b0, b1, b2, b3, a0, a1;

    b0 = *(const f16x8*)&smem[bb + brow + sk0];
    b1 = *(const f16x8*)&smem[bb + brow + 1024 + sk0];
    b2 = *(const f16x8*)&smem[bb + brow + 2048 + sk0];
    b3 = *(const f16x8*)&smem[bb + brow + 3072 + sk0];
    a0 = *(const f16x8*)&smem[ab + arow + sk0];
    a1 = *(const f16x8*)&smem[ab + arow + 1024 + sk0];
    if (pf) { SA(nb, t + 2, 0); SA(nb, t + 2, 1); }
    __builtin_amdgcn_s_barrier();
    LGKM0;
    __builtin_amdgcn_s_setprio(1);
    MF(0, 0, a0, b0); MF(0, 1, a0, b1); MF(0, 2, a0, b2); MF(0, 3, a0, b3);
    MF(1, 0, a1, b0); MF(1, 1, a1, b1); MF(1, 2, a1, b2); MF(1, 3, a1, b3);
    __builtin_amdgcn_s_setprio(0);
    __builtin_amdgcn_s_barrier();

    a0 = *(const f16x8*)&smem[ab + arow + 2048 + sk0];
    a1 = *(const f16x8*)&smem[ab + arow + 3072 + sk0];
    if (pf) { SB(nb, t + 2, 0); SB(nb, t + 2, 1); }
    __builtin_amdgcn_s_barrier();
    LGKM0;
    __builtin_amdgcn_s_setprio(1);
    MF(2, 0, a0, b0); MF(2, 1, a0, b1); MF(2, 2, a0, b2); MF(2, 3, a0, b3);
    MF(3, 0, a1, b0); MF(3, 1, a1, b1); MF(3, 2, a1, b2); MF(3, 3, a1, b3);
    __builtin_amdgcn_s_setprio(0);
    __builtin_amdgcn_s_barrier();

    b0 = *(const f16x8*)&smem[bb + brow + sk1];
    b1 = *(const f16x8*)&smem[bb + brow + 1024 + sk1];
    b2 = *(const f16x8*)&smem[bb + brow + 2048 + sk1];
    b3 = *(const f16x8*)&smem[bb + brow + 3072 + sk1];
    a0 = *(const f16x8*)&smem[ab + arow + sk1];
    a1 = *(const f16x8*)&smem[ab + arow + 1024 + sk1];
    if (pf) { SB(nb, t + 2, 2); SB(nb, t + 2, 3); }
    __builtin_amdgcn_s_barrier();
    LGKM0;
    __builtin_amdgcn_s_setprio(1);
    MF(0, 0, a0, b0); MF(0, 1, a0, b1); MF(0, 2, a0, b2); MF(0, 3, a0, b3);
    MF(1, 0, a1, b0); MF(1, 1, a1, b1); MF(1, 2, a1, b2); MF(1, 3, a1, b3);
    __builtin_amdgcn_s_setprio(0);
    __builtin_amdgcn_s_barrier();

    a0 = *(const f16x8*)&smem[ab + arow + 2048 + sk1];
    a1 = *(const f16x8*)&smem[ab + arow + 3072 + sk1];
    __builtin_amdgcn_s_barrier();
    LGKM0;
    __builtin_amdgcn_s_setprio(1);
    MF(2, 0, a0, b0); MF(2, 1, a0, b1); MF(2, 2, a0, b2); MF(2, 3, a0, b3);
    MF(3, 0, a1, b0); MF(3, 1, a1, b1); MF(3, 2, a1, b2); MF(3, 3, a1, b3);
    __builtin_amdgcn_s_setprio(0);
    if (t < 30) { VMC6; } else { VMC0; }
    __builtin_amdgcn_s_barrier();
    cur = (cur == 2) ? 0 : cur + 1;
  }
#undef SA
#undef SB
#undef MF

  const int rl0 = wr * 64 + t4 * 4;
  const int cl0 = wc * 64 + sl;
  if constexpr (MODE == 0) {
#pragma unroll
    for (int mi = 0; mi < 4; mi++) {
#pragma unroll
      for (int ni = 0; ni < 4; ni++) {
        const int col = col0 + cl0 + ni * 16;
        const float bi = bias1[col];
#pragma unroll
        for (int j = 0; j < 4; j++) {
          const int row = row0 + rl0 + mi * 16 + j;
          __builtin_nontemporal_store(acc[mi][ni][j] + bi, &outF[(size_t)row * DM + col]);
        }
      }
    }
  } else {
    const int region = col0 >> 11;
    const int c2 = col0 & 2047;
    __syncthreads();
    if (region == 2) {
#pragma unroll
      for (int mi = 0; mi < 4; mi++)
#pragma unroll
        for (int ni = 0; ni < 4; ni++) {
          const int cl = cl0 + ni * 16;
          const float bb2 = bias2[c2 + cl];
#pragma unroll
          for (int j = 0; j < 4; j++)
            smem[cl * 136 + rl0 + mi * 16 + j] = (f16)(acc[mi][ni][j] + bb2);
        }
      __syncthreads();
      const int b = row0 >> 11, s0 = row0 & 2047;
#pragma unroll
      for (int it = 0; it < 8; ++it) {
        const int ck = it * 512 + tid;
        const int ci = ck >> 4, cc = (ck & 15) * 8;
        const int dg = c2 + ci;
        *(f16x8*)&outV[((size_t)(b * 16 + (dg >> 7)) * HD + (dg & 127)) * SEQ + s0 + cc] =
            *(const f16x8*)&smem[ci * 136 + cc];
      }
    } else {
#pragma unroll
      for (int mi = 0; mi < 4; mi++)
#pragma unroll
        for (int ni = 0; ni < 4; ni++) {
          const int cl = cl0 + ni * 16;
          const int cg = c2 + cl;
          const float badd = (region == 0) ? bias1[cg] : 0.0f;
#pragma unroll
          for (int j = 0; j < 4; j++) {
            float v = acc[mi][ni][j] + badd;
            if (region == 0) v *= QSCALE;
            smem[(rl0 + mi * 16 + j) * 264 + cl] = (f16)v;
          }
        }
      __syncthreads();
      f16* const dst = (region == 0 ? outQ : outK) + (size_t)row0 * DM + c2;
#pragma unroll
      for (int it = 0; it < 8; ++it) {
        const int ck = it * 512 + tid;
        const int rr = ck >> 5, cc = (ck & 31) * 8;
        *(f16x8*)&dst[(size_t)rr * DM + cc] = *(const f16x8*)&smem[rr * 264 + cc];
      }
    }
  }
}

// ============================================================================
// Attention pass 1 (standalone): row sums of exp2(S'). 48 KiB LDS (3-buf K
// ring, 2-ahead prefetch, counted vmcnt(4)) -> 3 blocks/CU (+50% TLP vs fused).
// Writes inv = 1/rowsum to invg[bh*SEQ + row] (parked in the dead O region).
// ============================================================================
__global__ __launch_bounds__(256, 3) void attn_p1(const f16* __restrict__ Q,
                                                  const f16* __restrict__ Kt,
                                                  float* __restrict__ invg) {
  __shared__ __align__(16) f16 smem[24576];  // 48 KiB: bufs 0..2 @ i*8192
  const int tid = threadIdx.x, w = tid >> 6, l = tid & 63;
  const int t = l >> 4, sl = l & 15;

  const int flat = blockIdx.y * gridDim.x + blockIdx.x;
  const int swz = (flat & 7) * 128 + (flat >> 3);
  const int bh = swz >> 5, q0 = (swz & 31) * 64;

  const int b = bh >> 4, h = bh & 15;
  const f16* Qg = Q + (size_t)(b * SEQ) * DM + h * HD;
  const f16* Kg = Kt + (size_t)(b * SEQ) * DM + h * HD;

  // prologue: Q -> buf2, K0 -> buf0, K1 -> buf1
#pragma unroll
  for (int c = 0; c < 4; c++) {
    const int row = w * 16 + c * 4 + t;
    const int ch = sl ^ (row & 7);
    gload16(Qg + (size_t)(q0 + row) * DM + ch * 8, smem + 16384 + w * 2048 + c * 512);
    gload16(Kg + (size_t)row * DM + ch * 8, smem + w * 2048 + c * 512);
    gload16(Kg + (size_t)(64 + row) * DM + ch * 8, smem + 8192 + w * 2048 + c * 512);
  }
  __syncthreads();

  f16x8 qf[4];
  {
    const int row = w * 16 + sl;
#pragma unroll
    for (int g = 0; g < 4; g++) {
      const int ch = (g * 4 + t) ^ (row & 7);
      qf[g] = *(const f16x8*)&smem[16384 + row * 128 + ch * 8];
    }
  }
  // all waves done reading Q from buf2 before kb=0's prefetch (-> buf2) lands
  LGKM0;
  __builtin_amdgcn_s_barrier();

  float lsum = 0.0f;
  int cur = 0;  // buf of K(kb); prefetch target = (cur+2)%3 = cur==0?2:cur-1
#pragma unroll 1
  for (int kb = 0; kb < 32; ++kb) {
    f16* const kc = smem + cur * 8192;
    if (kb + 2 < 32) {
      f16* const kn = smem + ((cur == 0) ? 2 : cur - 1) * 8192;
#pragma unroll
      for (int c = 0; c < 4; c++) {
        const int row = w * 16 + c * 4 + t;
        const int ch = sl ^ (row & 7);
        gload16(Kg + (size_t)((kb + 2) * 64 + row) * DM + ch * 8, kn + w * 2048 + c * 512);
      }
    }
#pragma unroll
    for (int cb = 0; cb < 4; ++cb) {
      f32x4 s = {0.f, 0.f, 0.f, 0.f};
      const int key = cb * 16 + sl;
#pragma unroll
      for (int g = 0; g < 4; ++g) {
        const int ch = (g * 4 + t) ^ (key & 7);
        f16x8 kf = *(const f16x8*)&kc[key * 128 + ch * 8];
        s = __builtin_amdgcn_mfma_f32_16x16x32_f16(kf, qf[g], s, 0, 0, 0);
      }
#pragma unroll
      for (int j = 0; j < 4; j++) lsum += __builtin_amdgcn_exp2f(s[j]);
    }
    if (kb < 31) {
      if (kb + 2 < 32) { VMC4; } else { VMC0; }
      __builtin_amdgcn_s_barrier();
    }
    cur = (cur == 2) ? 0 : cur + 1;
  }
  lsum += __shfl_xor(lsum, 16);
  lsum += __shfl_xor(lsum, 32);
  if (t == 0) invg[(size_t)bh * SEQ + q0 + w * 16 + sl] = 1.0f / lsum;
}

// ============================================================================
// Attention pass 2 (standalone): recompute S, write normalized P (nt f32x4),
// accumulate PV. 72 KiB LDS (K/V dbuf + lP), 2 blocks/CU. Counted vmcnt(4):
// the 8 prefetch loads (older) drain, the <=4 P-stores stay in flight.
// ============================================================================
__global__ __launch_bounds__(256, 2) void attn_p2(const f16* __restrict__ Q,
                                                  const f16* __restrict__ Kt,
                                                  const f16* __restrict__ Vt,
                                                  const float* __restrict__ invg,
                                                  float* __restrict__ Pout,
                                                  f16* __restrict__ Oout) {
  __shared__ __align__(16) f16 smem[36864];  // 72 KiB
  // K @ (kb&1)*8192, V @ 16384+(kb&1)*8192 (Q staged in V0 slot first), lP @ 32768
  f16* const lP = smem + 32768;

  const int tid = threadIdx.x, w = tid >> 6, l = tid & 63;
  const int t = l >> 4, sl = l & 15, t8 = l >> 3, sl8 = l & 7;

  const int flat = blockIdx.y * gridDim.x + blockIdx.x;
  const int swz = (flat & 7) * 128 + (flat >> 3);
  const int bh = swz >> 5, q0 = (swz & 31) * 64;

  const int b = bh >> 4, h = bh & 15;
  const f16* Qg = Q + (size_t)(b * SEQ) * DM + h * HD;
  const f16* Kg = Kt + (size_t)(b * SEQ) * DM + h * HD;
  const f16* Vg = Vt + (size_t)bh * HD * SEQ;

  // prologue A: Q -> V0 slot, K0 -> K buf0
#pragma unroll
  for (int c = 0; c < 4; c++) {
    const int row = w * 16 + c * 4 + t;
    const int ch = sl ^ (row & 7);
    gload16(Qg + (size_t)(q0 + row) * DM + ch * 8, smem + 16384 + w * 2048 + c * 512);
    gload16(Kg + (size_t)row * DM + ch * 8, smem + w * 2048 + c * 512);
  }
  __syncthreads();

  const int qrow = w * 16 + sl;
  f16x8 qf[4];
#pragma unroll
  for (int g = 0; g < 4; g++) {
    const int ch = (g * 4 + t) ^ (qrow & 7);
    qf[g] = *(const f16x8*)&smem[16384 + qrow * 128 + ch * 8];
  }
  const float inv = invg[(size_t)bh * SEQ + q0 + qrow];
  // all waves done reading Q from the V0 slot before V0 is staged there
  LGKM0;
  __builtin_amdgcn_s_barrier();

  // prologue B: V0 -> V buf0
#pragma unroll
  for (int c = 0; c < 4; c++) {
    const int row = w * 32 + c * 8 + t8;
    const int ch = sl8 ^ (row & 7);
    gload16(Vg + (size_t)row * SEQ + ch * 8, smem + 16384 + w * 2048 + c * 512);
  }
  VMC0;
  __builtin_amdgcn_s_barrier();

  f32x4 oacc[8] = {};
  float* const Prow = Pout + ((size_t)bh * SEQ + q0 + qrow) * SEQ;

#pragma unroll 1
  for (int kb = 0; kb < 32; ++kb) {
    f16* const kc = smem + (kb & 1) * 8192;
    f16* const vc = smem + 16384 + (kb & 1) * 8192;
    if (kb < 31) {  // loads issued FIRST (older than the P stores below)
      f16* const kn = smem + ((kb + 1) & 1) * 8192;
      f16* const vn = smem + 16384 + ((kb + 1) & 1) * 8192;
#pragma unroll
      for (int c = 0; c < 4; c++) {
        const int row = w * 16 + c * 4 + t;
        const int ch = sl ^ (row & 7);
        gload16(Kg + (size_t)((kb + 1) * 64 + row) * DM + ch * 8, kn + w * 2048 + c * 512);
      }
#pragma unroll
      for (int c = 0; c < 4; c++) {
        const int row = w * 32 + c * 8 + t8;
        const int ch = sl8 ^ (row & 7);
        gload16(Vg + (size_t)row * SEQ + (kb + 1) * 64 + ch * 8, vn + w * 2048 + c * 512);
      }
    }
#pragma unroll
    for (int cb = 0; cb < 4; ++cb) {
      f32x4 s = {0.f, 0.f, 0.f, 0.f};
      const int key = cb * 16 + sl;
#pragma unroll
      for (int g = 0; g < 4; ++g) {
        const int ch = (g * 4 + t) ^ (key & 7);
        f16x8 kf = *(const f16x8*)&kc[key * 128 + ch * 8];
        s = __builtin_amdgcn_mfma_f32_16x16x32_f16(kf, qf[g], s, 0, 0, 0);
      }
      f32x4 p4;
      f16x4 ph;
#pragma unroll
      for (int j = 0; j < 4; j++) {
        const float p = __builtin_amdgcn_exp2f(s[j]) * inv;
        p4[j] = p;
        ph[j] = (f16)p;
      }
      __builtin_nontemporal_store(p4, (f32x4*)(Prow + kb * 64 + cb * 16 + t * 4));
      const int chs = (cb * 2 + (t >> 1)) ^ (qrow & 7);
      *(f16x4*)&lP[qrow * 64 + chs * 8 + (t & 1) * 4] = ph;
    }
    // lP rows are wave-private: ds ordering via lgkmcnt, no barrier needed
    f16x8 pf[2];
#pragma unroll
    for (int ks = 0; ks < 2; ++ks) {
      const int ch = (ks * 4 + t) ^ (qrow & 7);
      pf[ks] = *(const f16x8*)&lP[qrow * 64 + ch * 8];
    }
    __builtin_amdgcn_s_setprio(1);
#pragma unroll
    for (int cb = 0; cb < 8; ++cb) {
      const int d = cb * 16 + sl;
#pragma unroll
      for (int ks = 0; ks < 2; ++ks) {
        const int ch = (ks * 4 + t) ^ (d & 7);
        f16x8 vf = *(const f16x8*)&vc[d * 64 + ch * 8];
        oacc[cb] = __builtin_amdgcn_mfma_f32_16x16x32_f16(pf[ks], vf, oacc[cb], 0, 0, 0);
      }
    }
    __builtin_amdgcn_s_setprio(0);
    if (kb < 31) {
      VMC4;  // 8 loads (older) retired; <=4 P-stores may still be in flight
      __builtin_amdgcn_s_barrier();
    }
  }

  // O epilogue: [b,h,q,d] -> merged [n][2048] f16 for the final GEMM
#pragma unroll
  for (int cb = 0; cb < 8; ++cb) {
    const int d = cb * 16 + sl;
#pragma unroll
    for (int j = 0; j < 4; j++) {
      const int lrow = w * 16 + t * 4 + j;
      Oout[((size_t)(b * SEQ + q0 + lrow)) * DM + h * HD + d] = (f16)oacc[cb][j];
    }
  }
}

extern "C" void kernel_launch(void* const* d_in, const int* in_sizes, int n_in,
                              void* d_out, int out_size, void* d_ws, size_t ws_size,
                              hipStream_t stream) {
  const float* hs = (const float*)d_in[0];
  const float* Wq = (const float*)d_in[1];
  const float* bq = (const float*)d_in[2];
  const float* Wk = (const float*)d_in[3];
  const float* Wv = (const float*)d_in[4];
  const float* bv = (const float*)d_in[5];
  const float* Wo = (const float*)d_in[6];
  const float* bo = (const float*)d_in[7];
  float* out = (float*)d_out;
  float* Pout = out + (size_t)NT * DM;  // attn_weights region (134M f32)
  // inv scratch parked in the dead O region (overwritten by final O-GEMM)
  float* invg = out;

  // d_ws: 4 x 16 MiB f16 buffers (+ optional 8 MiB Wo16 if ws allows)
  f16* q16 = (f16*)d_ws;
  f16* k16 = q16 + (size_t)NT * DM;
  f16* vt16 = k16 + (size_t)NT * DM;
  f16* ao16 = vt16 + (size_t)NT * DM;
  f16* hs16 = (f16*)Pout;  // scratch inside P region (overwritten by attn_p2)
  f16* wqkv16 = hs16 + (size_t)NT * DM;  // [6144][2048] f16

  const bool bigws = ws_size >= (size_t)72 * 1024 * 1024 + 65536;
  f16* wo16 = bigws ? (ao16 + (size_t)NT * DM) : q16;

  cvt5_f32_f16<<<2048, 256, 0, stream>>>(hs, Wq, Wk, Wv, Wo, hs16, wqkv16, wo16,
                                         bigws ? 6 * 1048576 : 5 * 1048576);

  gemm8<3><<<dim3(6144 / 256, NT / 128), 512, 0, stream>>>(
      hs16, wqkv16, bq, bv, nullptr, q16, k16, vt16);

  attn_p1<<<dim3(SEQ / 64, NBH), 256, 0, stream>>>(q16, k16, invg);
  attn_p2<<<dim3(SEQ / 64, NBH), 256, 0, stream>>>(q16, k16, vt16, invg, Pout, ao16);

  if (!bigws) cvt_f32_f16<<<1024, 256, 0, stream>>>(Wo, wo16, DM * DM / 4);
  gemm8<0><<<dim3(DM / 256, NT / 128), 512, 0, stream>>>(
      ao16, wo16, bo, nullptr, out, nullptr, nullptr, nullptr);
}

// Round 12
// 380.645 us; speedup vs baseline: 1.0331x; 1.0331x over previous
//
#include <hip/hip_runtime.h>

typedef _Float16 f16;
typedef _Float16 f16x4 __attribute__((ext_vector_type(4)));
typedef _Float16 f16x8 __attribute__((ext_vector_type(8)));
typedef float f32x4 __attribute__((ext_vector_type(4)));

#define DM 2048
#define NT 4096
#define SEQ 2048
#define HD 128
#define NBH 32
// 1/sqrt(128) * log2(e): scores come out in log2 domain -> exp2 is one v_exp_f32
#define QSCALE (0.08838834764831845f * 1.4426950408889634f)

__device__ __forceinline__ void gload16(const f16* g, f16* l) {
  __builtin_amdgcn_global_load_lds(
      (const __attribute__((address_space(1))) void*)g,
      (__attribute__((address_space(3))) void*)l, 16, 0, 0);
}

#define LGKM0                                        \
  asm volatile("s_waitcnt lgkmcnt(0)" ::: "memory"); \
  __builtin_amdgcn_sched_barrier(0)
#define VMC6                                       \
  asm volatile("s_waitcnt vmcnt(6)" ::: "memory"); \
  __builtin_amdgcn_sched_barrier(0)
#define VMC4                                       \
  asm volatile("s_waitcnt vmcnt(4)" ::: "memory"); \
  __builtin_amdgcn_sched_barrier(0)
#define VMC0                                       \
  asm volatile("s_waitcnt vmcnt(0)" ::: "memory"); \
  __builtin_amdgcn_sched_barrier(0)

__global__ __launch_bounds__(256) void cvt_f32_f16(const float* __restrict__ src,
                                                   f16* __restrict__ dst, int n4) {
  int i = blockIdx.x * 256 + threadIdx.x;
  int st = gridDim.x * 256;
  for (; i < n4; i += st) {
    float4 v = ((const float4*)src)[i];
    f16x4 h = {(f16)v.x, (f16)v.y, (f16)v.z, (f16)v.w};
    ((f16x4*)dst)[i] = h;
  }
}

// merged convert: hs (2*2^20 f32x4) -> hsd, Wq/Wk/Wv -> wd concat, Wo -> wod
__global__ __launch_bounds__(256) void cvt5_f32_f16(
    const float* __restrict__ hs, const float* __restrict__ s0,
    const float* __restrict__ s1, const float* __restrict__ s2,
    const float* __restrict__ s3, f16* __restrict__ hsd, f16* __restrict__ wd,
    f16* __restrict__ wod, int n4) {
  int i = blockIdx.x * 256 + threadIdx.x;
  int st = gridDim.x * 256;
  for (; i < n4; i += st) {
    float4 v;
    f16x4 h;
    if (i < 2 * 1048576) {
      v = ((const float4*)hs)[i];
      h[0] = (f16)v.x; h[1] = (f16)v.y; h[2] = (f16)v.z; h[3] = (f16)v.w;
      ((f16x4*)hsd)[i] = h;
    } else {
      const int j = i - 2 * 1048576;
      const int r = j >> 20, jj = j & 1048575;
      const float* s = (r == 0) ? s0 : ((r == 1) ? s1 : ((r == 2) ? s2 : s3));
      v = ((const float4*)s)[jj];
      h[0] = (f16)v.x; h[1] = (f16)v.y; h[2] = (f16)v.z; h[3] = (f16)v.w;
      if (r < 3) ((f16x4*)wd)[j] = h;
      else ((f16x4*)wod)[jj] = h;
    }
  }
}

// ============================================================================
// 8-phase-style GEMM: C = A(4096x2048) * B^T, B row-major [N][2048].
// Tile BM=128 x BN=256, BK=64, 8 waves (2M x 4N), wave tile 64x64.
// Triple-buffered LDS, 2-ahead staging, counted vmcnt(6), XOR swizzle, setprio.
// ============================================================================
template <int MODE>
__global__ __launch_bounds__(512, 2) void gemm8(const f16* __restrict__ A,
                                                const f16* __restrict__ Bm,
                                                const float* __restrict__ bias1,
                                                const float* __restrict__ bias2,
                                                float* __restrict__ outF,
                                                f16* __restrict__ outQ,
                                                f16* __restrict__ outK,
                                                f16* __restrict__ outV) {
  __shared__ __align__(16) f16 smem[73728];  // 144 KiB -> 1 block/CU, 8 waves
  const int tid = threadIdx.x;
  const int w = tid >> 6, l = tid & 63;
  const int wr = w >> 2, wc = w & 3;  // 2M x 4N wave grid
  const int sl = l & 15, t4 = l >> 4;

  const int nbx = gridDim.x, nby = gridDim.y;
  const int flat = blockIdx.y * nbx + blockIdx.x;
  const int chunk = (nbx * nby) >> 3;
  const int swz = (flat & 7) * chunk + (flat >> 3);
  const int col0 = (swz / nby) * 256, row0 = (swz % nby) * 128;

  f32x4 acc[4][4] = {};

  const int sr8 = l >> 3;
  const int sch = (l & 7) ^ (sr8 & 7);
  const f16* gA0 = A + (size_t)(row0 + w * 8 + sr8) * DM + sch * 8;
  const f16* gB0 = Bm + (size_t)(col0 + w * 8 + sr8) * DM + sch * 8;

#define SA(tb, kt, r) \
  gload16(gA0 + (size_t)(r) * 64 * DM + (kt) * 64, smem + (tb) * 8192 + (r) * 4096 + w * 512)
#define SB(tb, kt, r)                               \
  gload16(gB0 + (size_t)(r) * 64 * DM + (kt) * 64, \
          smem + 24576 + (tb) * 16384 + (r) * 4096 + w * 512)
#define MF(mi, ni, av, bv) \
  acc[mi][ni] = __builtin_amdgcn_mfma_f32_16x16x32_f16(av, bv, acc[mi][ni], 0, 0, 0)

  const int sx = sl & 7;
  const int sk0 = (t4 ^ sx) * 8;
  const int sk1 = ((4 + t4) ^ sx) * 8;
  const int arow = (wr * 64 + sl) * 64;
  const int brow = (wc * 64 + sl) * 64;

  SA(0, 0, 0); SA(0, 0, 1);
  SB(0, 0, 0); SB(0, 0, 1); SB(0, 0, 2); SB(0, 0, 3);
  SA(1, 1, 0); SA(1, 1, 1);
  SB(1, 1, 0); SB(1, 1, 1); SB(1, 1, 2); SB(1, 1, 3);
  VMC6;
  __builtin_amdgcn_s_barrier();

  int cur = 0;
#pragma unroll 1
  for (int t = 0; t < 32; ++t) {
    const int nb = (cur == 0) ? 2 : cur - 1;
    const bool pf = (t + 2 < 32);
    const int ab = cur * 8192;
    const int bb = 24576 + cur * 16384;
    f16x8 b0, b1, b2, b3, a0, a1;

    b0 = *(const f16x8*)&smem[bb + brow + sk0];
    b1 = *(const f16x8*)&smem[bb + brow + 1024 + sk0];
    b2 = *(const f16x8*)&smem[bb + brow + 2048 + sk0];
    b3 = *(const f16x8*)&smem[bb + brow + 3072 + sk0];
    a0 = *(const f16x8*)&smem[ab + arow + sk0];
    a1 = *(const f16x8*)&smem[ab + arow + 1024 + sk0];
    if (pf) { SA(nb, t + 2, 0); SA(nb, t + 2, 1); }
    __builtin_amdgcn_s_barrier();
    LGKM0;
    __builtin_amdgcn_s_setprio(1);
    MF(0, 0, a0, b0); MF(0, 1, a0, b1); MF(0, 2, a0, b2); MF(0, 3, a0, b3);
    MF(1, 0, a1, b0); MF(1, 1, a1, b1); MF(1, 2, a1, b2); MF(1, 3, a1, b3);
    __builtin_amdgcn_s_setprio(0);
    __builtin_amdgcn_s_barrier();

    a0 = *(const f16x8*)&smem[ab + arow + 2048 + sk0];
    a1 = *(const f16x8*)&smem[ab + arow + 3072 + sk0];
    if (pf) { SB(nb, t + 2, 0); SB(nb, t + 2, 1); }
    __builtin_amdgcn_s_barrier();
    LGKM0;
    __builtin_amdgcn_s_setprio(1);
    MF(2, 0, a0, b0); MF(2, 1, a0, b1); MF(2, 2, a0, b2); MF(2, 3, a0, b3);
    MF(3, 0, a1, b0); MF(3, 1, a1, b1); MF(3, 2, a1, b2); MF(3, 3, a1, b3);
    __builtin_amdgcn_s_setprio(0);
    __builtin_amdgcn_s_barrier();

    b0 = *(const f16x8*)&smem[bb + brow + sk1];
    b1 = *(const f16x8*)&smem[bb + brow + 1024 + sk1];
    b2 = *(const f16x8*)&smem[bb + brow + 2048 + sk1];
    b3 = *(const f16x8*)&smem[bb + brow + 3072 + sk1];
    a0 = *(const f16x8*)&smem[ab + arow + sk1];
    a1 = *(const f16x8*)&smem[ab + arow + 1024 + sk1];
    if (pf) { SB(nb, t + 2, 2); SB(nb, t + 2, 3); }
    __builtin_amdgcn_s_barrier();
    LGKM0;
    __builtin_amdgcn_s_setprio(1);
    MF(0, 0, a0, b0); MF(0, 1, a0, b1); MF(0, 2, a0, b2); MF(0, 3, a0, b3);
    MF(1, 0, a1, b0); MF(1, 1, a1, b1); MF(1, 2, a1, b2); MF(1, 3, a1, b3);
    __builtin_amdgcn_s_setprio(0);
    __builtin_amdgcn_s_barrier();

    a0 = *(const f16x8*)&smem[ab + arow + 2048 + sk1];
    a1 = *(const f16x8*)&smem[ab + arow + 3072 + sk1];
    __builtin_amdgcn_s_barrier();
    LGKM0;
    __builtin_amdgcn_s_setprio(1);
    MF(2, 0, a0, b0); MF(2, 1, a0, b1); MF(2, 2, a0, b2); MF(2, 3, a0, b3);
    MF(3, 0, a1, b0); MF(3, 1, a1, b1); MF(3, 2, a1, b2); MF(3, 3, a1, b3);
    __builtin_amdgcn_s_setprio(0);
    if (t < 30) { VMC6; } else { VMC0; }
    __builtin_amdgcn_s_barrier();
    cur = (cur == 2) ? 0 : cur + 1;
  }
#undef SA
#undef SB
#undef MF

  const int rl0 = wr * 64 + t4 * 4;
  const int cl0 = wc * 64 + sl;
  if constexpr (MODE == 0) {
#pragma unroll
    for (int mi = 0; mi < 4; mi++) {
#pragma unroll
      for (int ni = 0; ni < 4; ni++) {
        const int col = col0 + cl0 + ni * 16;
        const float bi = bias1[col];
#pragma unroll
        for (int j = 0; j < 4; j++) {
          const int row = row0 + rl0 + mi * 16 + j;
          __builtin_nontemporal_store(acc[mi][ni][j] + bi, &outF[(size_t)row * DM + col]);
        }
      }
    }
  } else {
    const int region = col0 >> 11;
    const int c2 = col0 & 2047;
    __syncthreads();
    if (region == 2) {
#pragma unroll
      for (int mi = 0; mi < 4; mi++)
#pragma unroll
        for (int ni = 0; ni < 4; ni++) {
          const int cl = cl0 + ni * 16;
          const float bb2 = bias2[c2 + cl];
#pragma unroll
          for (int j = 0; j < 4; j++)
            smem[cl * 136 + rl0 + mi * 16 + j] = (f16)(acc[mi][ni][j] + bb2);
        }
      __syncthreads();
      const int b = row0 >> 11, s0 = row0 & 2047;
#pragma unroll
      for (int it = 0; it < 8; ++it) {
        const int ck = it * 512 + tid;
        const int ci = ck >> 4, cc = (ck & 15) * 8;
        const int dg = c2 + ci;
        *(f16x8*)&outV[((size_t)(b * 16 + (dg >> 7)) * HD + (dg & 127)) * SEQ + s0 + cc] =
            *(const f16x8*)&smem[ci * 136 + cc];
      }
    } else {
#pragma unroll
      for (int mi = 0; mi < 4; mi++)
#pragma unroll
        for (int ni = 0; ni < 4; ni++) {
          const int cl = cl0 + ni * 16;
          const int cg = c2 + cl;
          const float badd = (region == 0) ? bias1[cg] : 0.0f;
#pragma unroll
          for (int j = 0; j < 4; j++) {
            float v = acc[mi][ni][j] + badd;
            if (region == 0) v *= QSCALE;
            smem[(rl0 + mi * 16 + j) * 264 + cl] = (f16)v;
          }
        }
      __syncthreads();
      f16* const dst = (region == 0 ? outQ : outK) + (size_t)row0 * DM + c2;
#pragma unroll
      for (int it = 0; it < 8; ++it) {
        const int ck = it * 512 + tid;
        const int rr = ck >> 5, cc = (ck & 31) * 8;
        *(f16x8*)&dst[(size_t)rr * DM + cc] = *(const f16x8*)&smem[rr * 264 + cc];
      }
    }
  }
}

// ============================================================================
// Attention (round-9 proven structure): one block = 64 q rows of one (b,h).
// Pass 1: 4-deep K ring, 2-ahead prefetch, counted vmcnt(4), setprio on MFMA,
// 4-way lsum accumulators (breaks the serial VALU add chain).
// Pass 2: K/V dbuf, prefetch-before-stores, counted vmcnt(4).
// ============================================================================
__global__ __launch_bounds__(256, 2) void attn(const f16* __restrict__ Q,
                                               const f16* __restrict__ Kt,
                                               const f16* __restrict__ Vt,
                                               float* __restrict__ Pout,
                                               f16* __restrict__ Oout) {
  __shared__ __align__(16) f16 smem[36864];  // 72 KiB -> 2 blocks/CU
  // pass 1: K ring bufs 0..3 @ (kb&3)*8192; Q staged @16384 (buf2)
  // pass 2: K @ (kb&1)*8192, V @ 16384+(kb&1)*8192, lP @ 32768
  f16* const lP = smem + 32768;

  const int tid = threadIdx.x, w = tid >> 6, l = tid & 63;
  const int t = l >> 4, sl = l & 15, t8 = l >> 3, sl8 = l & 7;

  // XCD swizzle: each XCD owns 4 whole (b,h) -> K/V L2-resident
  const int flat = blockIdx.y * gridDim.x + blockIdx.x;
  const int swz = (flat & 7) * 128 + (flat >> 3);
  const int bh = swz >> 5, q0 = (swz & 31) * 64;

  const int b = bh >> 4, h = bh & 15;
  const f16* Qg = Q + (size_t)(b * SEQ) * DM + h * HD;
  const f16* Kg = Kt + (size_t)(b * SEQ) * DM + h * HD;
  const f16* Vg = Vt + (size_t)bh * HD * SEQ;

  // ---- prologue: Q -> buf2, K0 -> buf0, K1 -> buf1
#pragma unroll
  for (int c = 0; c < 4; c++) {
    const int row = w * 16 + c * 4 + t;
    const int ch = sl ^ (row & 7);
    gload16(Qg + (size_t)(q0 + row) * DM + ch * 8, smem + 16384 + w * 2048 + c * 512);
    gload16(Kg + (size_t)row * DM + ch * 8, smem + w * 2048 + c * 512);
    gload16(Kg + (size_t)(64 + row) * DM + ch * 8, smem + 8192 + w * 2048 + c * 512);
  }
  __syncthreads();

  f16x8 qf[4];
  {
    const int row = w * 16 + sl;
#pragma unroll
    for (int g = 0; g < 4; g++) {
      const int ch = (g * 4 + t) ^ (row & 7);
      qf[g] = *(const f16x8*)&smem[16384 + row * 128 + ch * 8];
    }
  }
  // all waves done reading Q from buf2 before pass-1 prefetch reuses it
  LGKM0;
  __builtin_amdgcn_s_barrier();

  float lsum4[4] = {0.f, 0.f, 0.f, 0.f};

  // ---- pass 1: row sums of exp2(S'), 4-deep K ring, 2-ahead prefetch
#pragma unroll 1
  for (int kb = 0; kb < 32; ++kb) {
    f16* const kc = smem + (kb & 3) * 8192;
    if (kb + 2 < 32) {
      f16* const kn = smem + ((kb + 2) & 3) * 8192;
#pragma unroll
      for (int c = 0; c < 4; c++) {
        const int row = w * 16 + c * 4 + t;
        const int ch = sl ^ (row & 7);
        gload16(Kg + (size_t)((kb + 2) * 64 + row) * DM + ch * 8, kn + w * 2048 + c * 512);
      }
    }
#pragma unroll
    for (int cb = 0; cb < 4; ++cb) {
      f32x4 s = {0.f, 0.f, 0.f, 0.f};
      const int key = cb * 16 + sl;
      __builtin_amdgcn_s_setprio(1);
#pragma unroll
      for (int g = 0; g < 4; ++g) {
        const int ch = (g * 4 + t) ^ (key & 7);
        f16x8 kf = *(const f16x8*)&kc[key * 128 + ch * 8];
        s = __builtin_amdgcn_mfma_f32_16x16x32_f16(kf, qf[g], s, 0, 0, 0);
      }
      __builtin_amdgcn_s_setprio(0);
#pragma unroll
      for (int j = 0; j < 4; j++) lsum4[j] += __builtin_amdgcn_exp2f(s[j]);
    }
    if (kb < 31) {
      if (kb + 2 < 32) { VMC4; } else { VMC0; }
      __builtin_amdgcn_s_barrier();
    }
  }
  float lsum = (lsum4[0] + lsum4[1]) + (lsum4[2] + lsum4[3]);
  lsum += __shfl_xor(lsum, 16);
  lsum += __shfl_xor(lsum, 32);
  const float inv = 1.0f / lsum;  // full row sum for qrow = w*16 + (l&15)

  // ---- pass 2 prologue: stage K0 + V0 (buf0 reads long since done)
  {
#pragma unroll
    for (int c = 0; c < 4; c++) {
      const int row = w * 16 + c * 4 + t;
      const int ch = sl ^ (row & 7);
      gload16(Kg + (size_t)row * DM + ch * 8, smem + w * 2048 + c * 512);
    }
#pragma unroll
    for (int c = 0; c < 4; c++) {
      const int row = w * 32 + c * 8 + t8;
      const int ch = sl8 ^ (row & 7);
      gload16(Vg + (size_t)row * SEQ + ch * 8, smem + 16384 + w * 2048 + c * 512);
    }
  }
  __syncthreads();

  f32x4 oacc[8] = {};
  const int qrow = w * 16 + sl;
  float* const Prow = Pout + ((size_t)bh * SEQ + q0 + qrow) * SEQ;

  // ---- pass 2: recompute S, write normalized P (nt f32x4), accumulate PV
#pragma unroll 1
  for (int kb = 0; kb < 32; ++kb) {
    f16* const kc = smem + (kb & 1) * 8192;
    f16* const vc = smem + 16384 + (kb & 1) * 8192;
    if (kb < 31) {  // loads issued FIRST (older than the P stores below)
      f16* const kn = smem + ((kb + 1) & 1) * 8192;
      f16* const vn = smem + 16384 + ((kb + 1) & 1) * 8192;
#pragma unroll
      for (int c = 0; c < 4; c++) {
        const int row = w * 16 + c * 4 + t;
        const int ch = sl ^ (row & 7);
        gload16(Kg + (size_t)((kb + 1) * 64 + row) * DM + ch * 8, kn + w * 2048 + c * 512);
      }
#pragma unroll
      for (int c = 0; c < 4; c++) {
        const int row = w * 32 + c * 8 + t8;
        const int ch = sl8 ^ (row & 7);
        gload16(Vg + (size_t)row * SEQ + (kb + 1) * 64 + ch * 8, vn + w * 2048 + c * 512);
      }
    }
#pragma unroll
    for (int cb = 0; cb < 4; ++cb) {
      f32x4 s = {0.f, 0.f, 0.f, 0.f};
      const int key = cb * 16 + sl;
#pragma unroll
      for (int g = 0; g < 4; ++g) {
        const int ch = (g * 4 + t) ^ (key & 7);
        f16x8 kf = *(const f16x8*)&kc[key * 128 + ch * 8];
        s = __builtin_amdgcn_mfma_f32_16x16x32_f16(kf, qf[g], s, 0, 0, 0);
      }
      f32x4 p4;
      f16x4 ph;
#pragma unroll
      for (int j = 0; j < 4; j++) {
        const float p = __builtin_amdgcn_exp2f(s[j]) * inv;
        p4[j] = p;
        ph[j] = (f16)p;
      }
      __builtin_nontemporal_store(p4, (f32x4*)(Prow + kb * 64 + cb * 16 + t * 4));
      const int chs = (cb * 2 + (t >> 1)) ^ (qrow & 7);
      *(f16x4*)&lP[qrow * 64 + chs * 8 + (t & 1) * 4] = ph;
    }
    // lP rows are wave-private: ds ordering via lgkmcnt, no barrier needed
    f16x8 pf[2];
#pragma unroll
    for (int ks = 0; ks < 2; ++ks) {
      const int ch = (ks * 4 + t) ^ (qrow & 7);
      pf[ks] = *(const f16x8*)&lP[qrow * 64 + ch * 8];
    }
    __builtin_amdgcn_s_setprio(1);
#pragma unroll
    for (int cb = 0; cb < 8; ++cb) {
      const int d = cb * 16 + sl;
#pragma unroll
      for (int ks = 0; ks < 2; ++ks) {
        const int ch = (ks * 4 + t) ^ (d & 7);
        f16x8 vf = *(const f16x8*)&vc[d * 64 + ch * 8];
        oacc[cb] = __builtin_amdgcn_mfma_f32_16x16x32_f16(pf[ks], vf, oacc[cb], 0, 0, 0);
      }
    }
    __builtin_amdgcn_s_setprio(0);
    if (kb < 31) {
      VMC4;  // 8 loads (older) retired; <=4 P-stores may still be in flight
      __builtin_amdgcn_s_barrier();
    }
  }

  // O epilogue: [b,h,q,d] -> merged [n][2048] f16 for the final GEMM
#pragma unroll
  for (int cb = 0; cb < 8; ++cb) {
    const int d = cb * 16 + sl;
#pragma unroll
    for (int j = 0; j < 4; j++) {
      const int lrow = w * 16 + t * 4 + j;
      Oout[((size_t)(b * SEQ + q0 + lrow)) * DM + h * HD + d] = (f16)oacc[cb][j];
    }
  }
}

extern "C" void kernel_launch(void* const* d_in, const int* in_sizes, int n_in,
                              void* d_out, int out_size, void* d_ws, size_t ws_size,
                              hipStream_t stream) {
  const float* hs = (const float*)d_in[0];
  const float* Wq = (const float*)d_in[1];
  const float* bq = (const float*)d_in[2];
  const float* Wk = (const float*)d_in[3];
  const float* Wv = (const float*)d_in[4];
  const float* bv = (const float*)d_in[5];
  const float* Wo = (const float*)d_in[6];
  const float* bo = (const float*)d_in[7];
  float* out = (float*)d_out;
  float* Pout = out + (size_t)NT * DM;  // attn_weights region (134M f32)

  // d_ws: 4 x 16 MiB f16 buffers (+ optional 8 MiB Wo16 if ws allows)
  f16* q16 = (f16*)d_ws;
  f16* k16 = q16 + (size_t)NT * DM;
  f16* vt16 = k16 + (size_t)NT * DM;
  f16* ao16 = vt16 + (size_t)NT * DM;
  f16* hs16 = (f16*)Pout;  // scratch inside P region (overwritten by attn)
  f16* wqkv16 = hs16 + (size_t)NT * DM;  // [6144][2048] f16

  const bool bigws = ws_size >= (size_t)72 * 1024 * 1024 + 65536;
  f16* wo16 = bigws ? (ao16 + (size_t)NT * DM) : q16;

  cvt5_f32_f16<<<2048, 256, 0, stream>>>(hs, Wq, Wk, Wv, Wo, hs16, wqkv16, wo16,
                                         bigws ? 6 * 1048576 : 5 * 1048576);

  gemm8<3><<<dim3(6144 / 256, NT / 128), 512, 0, stream>>>(
      hs16, wqkv16, bq, bv, nullptr, q16, k16, vt16);

  attn<<<dim3(SEQ / 64, NBH), 256, 0, stream>>>(q16, k16, vt16, Pout, ao16);

  if (!bigws) cvt_f32_f16<<<1024, 256, 0, stream>>>(Wo, wo16, DM * DM / 4);
  gemm8<0><<<dim3(DM / 256, NT / 128), 512, 0, stream>>>(
      ao16, wo16, bo, nullptr, out, nullptr, nullptr, nullptr);
}

// Round 13
// 373.735 us; speedup vs baseline: 1.0522x; 1.0185x over previous
//
#include <hip/hip_runtime.h>

typedef _Float16 f16;
typedef _Float16 f16x4 __attribute__((ext_vector_type(4)));
typedef _Float16 f16x8 __attribute__((ext_vector_type(8)));
typedef float f32x4 __attribute__((ext_vector_type(4)));

#define DM 2048
#define NT 4096
#define SEQ 2048
#define HD 128
#define NBH 32
// 1/sqrt(128) * log2(e): scores come out in log2 domain -> exp2 is one v_exp_f32
#define QSCALE (0.08838834764831845f * 1.4426950408889634f)

__device__ __forceinline__ void gload16(const f16* g, f16* l) {
  __builtin_amdgcn_global_load_lds(
      (const __attribute__((address_space(1))) void*)g,
      (__attribute__((address_space(3))) void*)l, 16, 0, 0);
}

#define LGKM0                                        \
  asm volatile("s_waitcnt lgkmcnt(0)" ::: "memory"); \
  __builtin_amdgcn_sched_barrier(0)
#define VMC6                                       \
  asm volatile("s_waitcnt vmcnt(6)" ::: "memory"); \
  __builtin_amdgcn_sched_barrier(0)
#define VMC4                                       \
  asm volatile("s_waitcnt vmcnt(4)" ::: "memory"); \
  __builtin_amdgcn_sched_barrier(0)
#define VMC0                                       \
  asm volatile("s_waitcnt vmcnt(0)" ::: "memory"); \
  __builtin_amdgcn_sched_barrier(0)

__global__ __launch_bounds__(256) void cvt_f32_f16(const float* __restrict__ src,
                                                   f16* __restrict__ dst, int n4) {
  int i = blockIdx.x * 256 + threadIdx.x;
  int st = gridDim.x * 256;
  for (; i < n4; i += st) {
    float4 v = ((const float4*)src)[i];
    f16x4 h = {(f16)v.x, (f16)v.y, (f16)v.z, (f16)v.w};
    ((f16x4*)dst)[i] = h;
  }
}

// merged convert: hs (2*2^20 f32x4) -> hsd, Wq/Wk/Wv -> wd concat, Wo -> wod
__global__ __launch_bounds__(256) void cvt5_f32_f16(
    const float* __restrict__ hs, const float* __restrict__ s0,
    const float* __restrict__ s1, const float* __restrict__ s2,
    const float* __restrict__ s3, f16* __restrict__ hsd, f16* __restrict__ wd,
    f16* __restrict__ wod, int n4) {
  int i = blockIdx.x * 256 + threadIdx.x;
  int st = gridDim.x * 256;
  for (; i < n4; i += st) {
    float4 v;
    f16x4 h;
    if (i < 2 * 1048576) {
      v = ((const float4*)hs)[i];
      h[0] = (f16)v.x; h[1] = (f16)v.y; h[2] = (f16)v.z; h[3] = (f16)v.w;
      ((f16x4*)hsd)[i] = h;
    } else {
      const int j = i - 2 * 1048576;
      const int r = j >> 20, jj = j & 1048575;
      const float* s = (r == 0) ? s0 : ((r == 1) ? s1 : ((r == 2) ? s2 : s3));
      v = ((const float4*)s)[jj];
      h[0] = (f16)v.x; h[1] = (f16)v.y; h[2] = (f16)v.z; h[3] = (f16)v.w;
      if (r < 3) ((f16x4*)wd)[j] = h;
      else ((f16x4*)wod)[jj] = h;
    }
  }
}

// ============================================================================
// 8-phase-style GEMM: C = A(4096x2048) * B^T, B row-major [N][2048].
// Tile BM=128 x BN=256, BK=64, 8 waves (2M x 4N), wave tile 64x64.
// Triple-buffered LDS, 2-ahead staging, counted vmcnt(6), XOR swizzle, setprio.
// ============================================================================
template <int MODE>
__global__ __launch_bounds__(512, 2) void gemm8(const f16* __restrict__ A,
                                                const f16* __restrict__ Bm,
                                                const float* __restrict__ bias1,
                                                const float* __restrict__ bias2,
                                                float* __restrict__ outF,
                                                f16* __restrict__ outQ,
                                                f16* __restrict__ outK,
                                                f16* __restrict__ outV) {
  __shared__ __align__(16) f16 smem[73728];  // 144 KiB -> 1 block/CU, 8 waves
  const int tid = threadIdx.x;
  const int w = tid >> 6, l = tid & 63;
  const int wr = w >> 2, wc = w & 3;  // 2M x 4N wave grid
  const int sl = l & 15, t4 = l >> 4;

  const int nbx = gridDim.x, nby = gridDim.y;
  const int flat = blockIdx.y * nbx + blockIdx.x;
  const int chunk = (nbx * nby) >> 3;
  const int swz = (flat & 7) * chunk + (flat >> 3);
  const int col0 = (swz / nby) * 256, row0 = (swz % nby) * 128;

  f32x4 acc[4][4] = {};

  const int sr8 = l >> 3;
  const int sch = (l & 7) ^ (sr8 & 7);
  const f16* gA0 = A + (size_t)(row0 + w * 8 + sr8) * DM + sch * 8;
  const f16* gB0 = Bm + (size_t)(col0 + w * 8 + sr8) * DM + sch * 8;

#define SA(tb, kt, r) \
  gload16(gA0 + (size_t)(r) * 64 * DM + (kt) * 64, smem + (tb) * 8192 + (r) * 4096 + w * 512)
#define SB(tb, kt, r)                               \
  gload16(gB0 + (size_t)(r) * 64 * DM + (kt) * 64, \
          smem + 24576 + (tb) * 16384 + (r) * 4096 + w * 512)
#define MF(mi, ni, av, bv) \
  acc[mi][ni] = __builtin_amdgcn_mfma_f32_16x16x32_f16(av, bv, acc[mi][ni], 0, 0, 0)

  const int sx = sl & 7;
  const int sk0 = (t4 ^ sx) * 8;
  const int sk1 = ((4 + t4) ^ sx) * 8;
  const int arow = (wr * 64 + sl) * 64;
  const int brow = (wc * 64 + sl) * 64;

  SA(0, 0, 0); SA(0, 0, 1);
  SB(0, 0, 0); SB(0, 0, 1); SB(0, 0, 2); SB(0, 0, 3);
  SA(1, 1, 0); SA(1, 1, 1);
  SB(1, 1, 0); SB(1, 1, 1); SB(1, 1, 2); SB(1, 1, 3);
  VMC6;
  __builtin_amdgcn_s_barrier();

  int cur = 0;
#pragma unroll 1
  for (int t = 0; t < 32; ++t) {
    const int nb = (cur == 0) ? 2 : cur - 1;
    const bool pf = (t + 2 < 32);
    const int ab = cur * 8192;
    const int bb = 24576 + cur * 16384;
    f16x8 b0, b1, b2, b3, a0, a1;

    b0 = *(const f16x8*)&smem[bb + brow + sk0];
    b1 = *(const f16x8*)&smem[bb + brow + 1024 + sk0];
    b2 = *(const f16x8*)&smem[bb + brow + 2048 + sk0];
    b3 = *(const f16x8*)&smem[bb + brow + 3072 + sk0];
    a0 = *(const f16x8*)&smem[ab + arow + sk0];
    a1 = *(const f16x8*)&smem[ab + arow + 1024 + sk0];
    if (pf) { SA(nb, t + 2, 0); SA(nb, t + 2, 1); }
    __builtin_amdgcn_s_barrier();
    LGKM0;
    __builtin_amdgcn_s_setprio(1);
    MF(0, 0, a0, b0); MF(0, 1, a0, b1); MF(0, 2, a0, b2); MF(0, 3, a0, b3);
    MF(1, 0, a1, b0); MF(1, 1, a1, b1); MF(1, 2, a1, b2); MF(1, 3, a1, b3);
    __builtin_amdgcn_s_setprio(0);
    __builtin_amdgcn_s_barrier();

    a0 = *(const f16x8*)&smem[ab + arow + 2048 + sk0];
    a1 = *(const f16x8*)&smem[ab + arow + 3072 + sk0];
    if (pf) { SB(nb, t + 2, 0); SB(nb, t + 2, 1); }
    __builtin_amdgcn_s_barrier();
    LGKM0;
    __builtin_amdgcn_s_setprio(1);
    MF(2, 0, a0, b0); MF(2, 1, a0, b1); MF(2, 2, a0, b2); MF(2, 3, a0, b3);
    MF(3, 0, a1, b0); MF(3, 1, a1, b1); MF(3, 2, a1, b2); MF(3, 3, a1, b3);
    __builtin_amdgcn_s_setprio(0);
    __builtin_amdgcn_s_barrier();

    b0 = *(const f16x8*)&smem[bb + brow + sk1];
    b1 = *(const f16x8*)&smem[bb + brow + 1024 + sk1];
    b2 = *(const f16x8*)&smem[bb + brow + 2048 + sk1];
    b3 = *(const f16x8*)&smem[bb + brow + 3072 + sk1];
    a0 = *(const f16x8*)&smem[ab + arow + sk1];
    a1 = *(const f16x8*)&smem[ab + arow + 1024 + sk1];
    if (pf) { SB(nb, t + 2, 2); SB(nb, t + 2, 3); }
    __builtin_amdgcn_s_barrier();
    LGKM0;
    __builtin_amdgcn_s_setprio(1);
    MF(0, 0, a0, b0); MF(0, 1, a0, b1); MF(0, 2, a0, b2); MF(0, 3, a0, b3);
    MF(1, 0, a1, b0); MF(1, 1, a1, b1); MF(1, 2, a1, b2); MF(1, 3, a1, b3);
    __builtin_amdgcn_s_setprio(0);
    __builtin_amdgcn_s_barrier();

    a0 = *(const f16x8*)&smem[ab + arow + 2048 + sk1];
    a1 = *(const f16x8*)&smem[ab + arow + 3072 + sk1];
    __builtin_amdgcn_s_barrier();
    LGKM0;
    __builtin_amdgcn_s_setprio(1);
    MF(2, 0, a0, b0); MF(2, 1, a0, b1); MF(2, 2, a0, b2); MF(2, 3, a0, b3);
    MF(3, 0, a1, b0); MF(3, 1, a1, b1); MF(3, 2, a1, b2); MF(3, 3, a1, b3);
    __builtin_amdgcn_s_setprio(0);
    if (t < 30) { VMC6; } else { VMC0; }
    __builtin_amdgcn_s_barrier();
    cur = (cur == 2) ? 0 : cur + 1;
  }
#undef SA
#undef SB
#undef MF

  const int rl0 = wr * 64 + t4 * 4;
  const int cl0 = wc * 64 + sl;
  if constexpr (MODE == 0) {
#pragma unroll
    for (int mi = 0; mi < 4; mi++) {
#pragma unroll
      for (int ni = 0; ni < 4; ni++) {
        const int col = col0 + cl0 + ni * 16;
        const float bi = bias1[col];
#pragma unroll
        for (int j = 0; j < 4; j++) {
          const int row = row0 + rl0 + mi * 16 + j;
          __builtin_nontemporal_store(acc[mi][ni][j] + bi, &outF[(size_t)row * DM + col]);
        }
      }
    }
  } else {
    const int region = col0 >> 11;
    const int c2 = col0 & 2047;
    __syncthreads();
    if (region == 2) {
#pragma unroll
      for (int mi = 0; mi < 4; mi++)
#pragma unroll
        for (int ni = 0; ni < 4; ni++) {
          const int cl = cl0 + ni * 16;
          const float bb2 = bias2[c2 + cl];
#pragma unroll
          for (int j = 0; j < 4; j++)
            smem[cl * 136 + rl0 + mi * 16 + j] = (f16)(acc[mi][ni][j] + bb2);
        }
      __syncthreads();
      const int b = row0 >> 11, s0 = row0 & 2047;
#pragma unroll
      for (int it = 0; it < 8; ++it) {
        const int ck = it * 512 + tid;
        const int ci = ck >> 4, cc = (ck & 15) * 8;
        const int dg = c2 + ci;
        *(f16x8*)&outV[((size_t)(b * 16 + (dg >> 7)) * HD + (dg & 127)) * SEQ + s0 + cc] =
            *(const f16x8*)&smem[ci * 136 + cc];
      }
    } else {
#pragma unroll
      for (int mi = 0; mi < 4; mi++)
#pragma unroll
        for (int ni = 0; ni < 4; ni++) {
          const int cl = cl0 + ni * 16;
          const int cg = c2 + cl;
          const float badd = (region == 0) ? bias1[cg] : 0.0f;
#pragma unroll
          for (int j = 0; j < 4; j++) {
            float v = acc[mi][ni][j] + badd;
            if (region == 0) v *= QSCALE;
            smem[(rl0 + mi * 16 + j) * 264 + cl] = (f16)v;
          }
        }
      __syncthreads();
      f16* const dst = (region == 0 ? outQ : outK) + (size_t)row0 * DM + c2;
#pragma unroll
      for (int it = 0; it < 8; ++it) {
        const int ck = it * 512 + tid;
        const int rr = ck >> 5, cc = (ck & 31) * 8;
        *(f16x8*)&dst[(size_t)rr * DM + cc] = *(const f16x8*)&smem[rr * 264 + cc];
      }
    }
  }
}

// ============================================================================
// Attention: one block = 64 q rows of one (b,h).
// Pass 1 (KEY-SLICED): wave w owns keys w*16..w*16+15 for ALL 64 q-rows.
// Q fragments for all 4 row-groups live in registers (loop-invariant, 64 VGPR)
// -> kf LDS reads drop 16 -> 4 per wave per iteration (4x less LDS traffic).
// Rowsum = shfl-over-t + tiny cross-wave LDS reduce.
// Pass 2: proven round-9 structure, unchanged (K/V dbuf, prefetch-before-
// stores, counted vmcnt(4)).
// ============================================================================
__global__ __launch_bounds__(256, 2) void attn(const f16* __restrict__ Q,
                                               const f16* __restrict__ Kt,
                                               const f16* __restrict__ Vt,
                                               float* __restrict__ Pout,
                                               f16* __restrict__ Oout) {
  __shared__ __align__(16) f16 smem[36864];  // 72 KiB -> 2 blocks/CU
  // pass 1: K ring bufs 0..3 @ (kb&3)*8192; Q staged @16384 (buf2);
  //         cross-wave partials @ byte 65536 (lP area, dead in pass 1)
  // pass 2: K @ (kb&1)*8192, V @ 16384+(kb&1)*8192, lP @ 32768
  f16* const lP = smem + 32768;

  const int tid = threadIdx.x, w = tid >> 6, l = tid & 63;
  const int t = l >> 4, sl = l & 15, t8 = l >> 3, sl8 = l & 7;

  // XCD swizzle: each XCD owns 4 whole (b,h) -> K/V L2-resident
  const int flat = blockIdx.y * gridDim.x + blockIdx.x;
  const int swz = (flat & 7) * 128 + (flat >> 3);
  const int bh = swz >> 5, q0 = (swz & 31) * 64;

  const int b = bh >> 4, h = bh & 15;
  const f16* Qg = Q + (size_t)(b * SEQ) * DM + h * HD;
  const f16* Kg = Kt + (size_t)(b * SEQ) * DM + h * HD;
  const f16* Vg = Vt + (size_t)bh * HD * SEQ;

  // ---- prologue: Q -> buf2, K0 -> buf0, K1 -> buf1
#pragma unroll
  for (int c = 0; c < 4; c++) {
    const int row = w * 16 + c * 4 + t;
    const int ch = sl ^ (row & 7);
    gload16(Qg + (size_t)(q0 + row) * DM + ch * 8, smem + 16384 + w * 2048 + c * 512);
    gload16(Kg + (size_t)row * DM + ch * 8, smem + w * 2048 + c * 512);
    gload16(Kg + (size_t)(64 + row) * DM + ch * 8, smem + 8192 + w * 2048 + c * 512);
  }
  __syncthreads();

  // Q fragments for ALL 4 row-groups (loop-invariant; row&7 == sl&7 for all u)
  f16x8 qfa[4][4];
#pragma unroll
  for (int u = 0; u < 4; u++) {
    const int row = u * 16 + sl;
#pragma unroll
    for (int g = 0; g < 4; g++) {
      const int ch = (g * 4 + t) ^ (row & 7);
      qfa[u][g] = *(const f16x8*)&smem[16384 + row * 128 + ch * 8];
    }
  }
  // all waves done reading Q from buf2 before pass-1 prefetch reuses it
  LGKM0;
  __builtin_amdgcn_s_barrier();

  // ---- pass 1: key-sliced. Wave w's keys: w*16+sl (A-rows); loop over
  // row-groups u. Lane ends up with S[key = w*16 + t*4+j][qrow = u*16+sl].
  float lsum[4] = {0.f, 0.f, 0.f, 0.f};
  const int mykey = w * 16 + sl;  // key&7 == sl&7
#pragma unroll 1
  for (int kb = 0; kb < 32; ++kb) {
    f16* const kc = smem + (kb & 3) * 8192;
    if (kb + 2 < 32) {
      f16* const kn = smem + ((kb + 2) & 3) * 8192;
#pragma unroll
      for (int c = 0; c < 4; c++) {
        const int row = w * 16 + c * 4 + t;
        const int ch = sl ^ (row & 7);
        gload16(Kg + (size_t)((kb + 2) * 64 + row) * DM + ch * 8, kn + w * 2048 + c * 512);
      }
    }
    f16x8 kf[4];
#pragma unroll
    for (int g = 0; g < 4; ++g) {
      const int ch = (g * 4 + t) ^ (mykey & 7);
      kf[g] = *(const f16x8*)&kc[mykey * 128 + ch * 8];
    }
    __builtin_amdgcn_s_setprio(1);
#pragma unroll
    for (int u = 0; u < 4; ++u) {
      f32x4 s = {0.f, 0.f, 0.f, 0.f};
#pragma unroll
      for (int g = 0; g < 4; ++g)
        s = __builtin_amdgcn_mfma_f32_16x16x32_f16(kf[g], qfa[u][g], s, 0, 0, 0);
#pragma unroll
      for (int j = 0; j < 4; j++) lsum[u] += __builtin_amdgcn_exp2f(s[j]);
    }
    __builtin_amdgcn_s_setprio(0);
    if (kb < 31) {
      if (kb + 2 < 32) { VMC4; } else { VMC0; }
      __builtin_amdgcn_s_barrier();
    }
  }
  // reduce over t (keys t*4..t*4+3 within the wave's 16-key slice)
#pragma unroll
  for (int u = 0; u < 4; u++) {
    lsum[u] += __shfl_xor(lsum[u], 16);
    lsum[u] += __shfl_xor(lsum[u], 32);
  }
  // cross-wave reduce via LDS partials (lP area, dead in pass 1)
  float* const part = (float*)(smem + 32768);
  if (t == 0) {
#pragma unroll
    for (int u = 0; u < 4; u++) part[w * 64 + u * 16 + sl] = lsum[u];
  }
  __syncthreads();
  const int qrow = w * 16 + sl;  // pass-2 row ownership
  const float inv =
      1.0f / (part[qrow] + part[64 + qrow] + part[128 + qrow] + part[192 + qrow]);
  // pass-2 qf = qfa[w] (wave-uniform compile-time select, no scratch)
  f16x8 qf[4];
#pragma unroll
  for (int g = 0; g < 4; g++)
    qf[g] = (w == 0) ? qfa[0][g] : (w == 1) ? qfa[1][g] : (w == 2) ? qfa[2][g] : qfa[3][g];

  // ---- pass 2 prologue: stage K0 + V0 (buf0 reads long since done)
  {
#pragma unroll
    for (int c = 0; c < 4; c++) {
      const int row = w * 16 + c * 4 + t;
      const int ch = sl ^ (row & 7);
      gload16(Kg + (size_t)row * DM + ch * 8, smem + w * 2048 + c * 512);
    }
#pragma unroll
    for (int c = 0; c < 4; c++) {
      const int row = w * 32 + c * 8 + t8;
      const int ch = sl8 ^ (row & 7);
      gload16(Vg + (size_t)row * SEQ + ch * 8, smem + 16384 + w * 2048 + c * 512);
    }
  }
  __syncthreads();

  f32x4 oacc[8] = {};
  float* const Prow = Pout + ((size_t)bh * SEQ + q0 + qrow) * SEQ;

  // ---- pass 2: recompute S, write normalized P (nt f32x4), accumulate PV
#pragma unroll 1
  for (int kb = 0; kb < 32; ++kb) {
    f16* const kc = smem + (kb & 1) * 8192;
    f16* const vc = smem + 16384 + (kb & 1) * 8192;
    if (kb < 31) {  // loads issued FIRST (older than the P stores below)
      f16* const kn = smem + ((kb + 1) & 1) * 8192;
      f16* const vn = smem + 16384 + ((kb + 1) & 1) * 8192;
#pragma unroll
      for (int c = 0; c < 4; c++) {
        const int row = w * 16 + c * 4 + t;
        const int ch = sl ^ (row & 7);
        gload16(Kg + (size_t)((kb + 1) * 64 + row) * DM + ch * 8, kn + w * 2048 + c * 512);
      }
#pragma unroll
      for (int c = 0; c < 4; c++) {
        const int row = w * 32 + c * 8 + t8;
        const int ch = sl8 ^ (row & 7);
        gload16(Vg + (size_t)row * SEQ + (kb + 1) * 64 + ch * 8, vn + w * 2048 + c * 512);
      }
    }
#pragma unroll
    for (int cb = 0; cb < 4; ++cb) {
      f32x4 s = {0.f, 0.f, 0.f, 0.f};
      const int key = cb * 16 + sl;
#pragma unroll
      for (int g = 0; g < 4; ++g) {
        const int ch = (g * 4 + t) ^ (key & 7);
        f16x8 kf = *(const f16x8*)&kc[key * 128 + ch * 8];
        s = __builtin_amdgcn_mfma_f32_16x16x32_f16(kf, qf[g], s, 0, 0, 0);
      }
      f32x4 p4;
      f16x4 ph;
#pragma unroll
      for (int j = 0; j < 4; j++) {
        const float p = __builtin_amdgcn_exp2f(s[j]) * inv;
        p4[j] = p;
        ph[j] = (f16)p;
      }
      __builtin_nontemporal_store(p4, (f32x4*)(Prow + kb * 64 + cb * 16 + t * 4));
      const int chs = (cb * 2 + (t >> 1)) ^ (qrow & 7);
      *(f16x4*)&lP[qrow * 64 + chs * 8 + (t & 1) * 4] = ph;
    }
    // lP rows are wave-private: ds ordering via lgkmcnt, no barrier needed
    f16x8 pf[2];
#pragma unroll
    for (int ks = 0; ks < 2; ++ks) {
      const int ch = (ks * 4 + t) ^ (qrow & 7);
      pf[ks] = *(const f16x8*)&lP[qrow * 64 + ch * 8];
    }
    __builtin_amdgcn_s_setprio(1);
#pragma unroll
    for (int cb = 0; cb < 8; ++cb) {
      const int d = cb * 16 + sl;
#pragma unroll
      for (int ks = 0; ks < 2; ++ks) {
        const int ch = (ks * 4 + t) ^ (d & 7);
        f16x8 vf = *(const f16x8*)&vc[d * 64 + ch * 8];
        oacc[cb] = __builtin_amdgcn_mfma_f32_16x16x32_f16(pf[ks], vf, oacc[cb], 0, 0, 0);
      }
    }
    __builtin_amdgcn_s_setprio(0);
    if (kb < 31) {
      VMC4;  // 8 loads (older) retired; <=4 P-stores may still be in flight
      __builtin_amdgcn_s_barrier();
    }
  }

  // O epilogue: [b,h,q,d] -> merged [n][2048] f16 for the final GEMM
#pragma unroll
  for (int cb = 0; cb < 8; ++cb) {
    const int d = cb * 16 + sl;
#pragma unroll
    for (int j = 0; j < 4; j++) {
      const int lrow = w * 16 + t * 4 + j;
      Oout[((size_t)(b * SEQ + q0 + lrow)) * DM + h * HD + d] = (f16)oacc[cb][j];
    }
  }
}

extern "C" void kernel_launch(void* const* d_in, const int* in_sizes, int n_in,
                              void* d_out, int out_size, void* d_ws, size_t ws_size,
                              hipStream_t stream) {
  const float* hs = (const float*)d_in[0];
  const float* Wq = (const float*)d_in[1];
  const float* bq = (const float*)d_in[2];
  const float* Wk = (const float*)d_in[3];
  const float* Wv = (const float*)d_in[4];
  const float* bv = (const float*)d_in[5];
  const float* Wo = (const float*)d_in[6];
  const float* bo = (const float*)d_in[7];
  float* out = (float*)d_out;
  float* Pout = out + (size_t)NT * DM;  // attn_weights region (134M f32)

  // d_ws: 4 x 16 MiB f16 buffers (+ optional 8 MiB Wo16 if ws allows)
  f16* q16 = (f16*)d_ws;
  f16* k16 = q16 + (size_t)NT * DM;
  f16* vt16 = k16 + (size_t)NT * DM;
  f16* ao16 = vt16 + (size_t)NT * DM;
  f16* hs16 = (f16*)Pout;  // scratch inside P region (overwritten by attn)
  f16* wqkv16 = hs16 + (size_t)NT * DM;  // [6144][2048] f16

  const bool bigws = ws_size >= (size_t)72 * 1024 * 1024 + 65536;
  f16* wo16 = bigws ? (ao16 + (size_t)NT * DM) : q16;

  cvt5_f32_f16<<<2048, 256, 0, stream>>>(hs, Wq, Wk, Wv, Wo, hs16, wqkv16, wo16,
                                         bigws ? 6 * 1048576 : 5 * 1048576);

  gemm8<3><<<dim3(6144 / 256, NT / 128), 512, 0, stream>>>(
      hs16, wqkv16, bq, bv, nullptr, q16, k16, vt16);

  attn<<<dim3(SEQ / 64, NBH), 256, 0, stream>>>(q16, k16, vt16, Pout, ao16);

  if (!bigws) cvt_f32_f16<<<1024, 256, 0, stream>>>(Wo, wo16, DM * DM / 4);
  gemm8<0><<<dim3(DM / 256, NT / 128), 512, 0, stream>>>(
      ao16, wo16, bo, nullptr, out, nullptr, nullptr, nullptr);
}

// Round 14
// 363.074 us; speedup vs baseline: 1.0831x; 1.0294x over previous
//
#include <hip/hip_runtime.h>

typedef _Float16 f16;
typedef _Float16 f16x4 __attribute__((ext_vector_type(4)));
typedef _Float16 f16x8 __attribute__((ext_vector_type(8)));
typedef float f32x4 __attribute__((ext_vector_type(4)));

#define DM 2048
#define NT 4096
#define SEQ 2048
#define HD 128
#define NBH 32
// 1/sqrt(128) * log2(e): scores come out in log2 domain -> exp2 is one v_exp_f32
#define QSCALE (0.08838834764831845f * 1.4426950408889634f)

__device__ __forceinline__ void gload16(const f16* g, f16* l) {
  __builtin_amdgcn_global_load_lds(
      (const __attribute__((address_space(1))) void*)g,
      (__attribute__((address_space(3))) void*)l, 16, 0, 0);
}

#define LGKM0                                        \
  asm volatile("s_waitcnt lgkmcnt(0)" ::: "memory"); \
  __builtin_amdgcn_sched_barrier(0)
#define VMC6                                       \
  asm volatile("s_waitcnt vmcnt(6)" ::: "memory"); \
  __builtin_amdgcn_sched_barrier(0)
#define VMC4                                       \
  asm volatile("s_waitcnt vmcnt(4)" ::: "memory"); \
  __builtin_amdgcn_sched_barrier(0)
#define VMC0                                       \
  asm volatile("s_waitcnt vmcnt(0)" ::: "memory"); \
  __builtin_amdgcn_sched_barrier(0)

__global__ __launch_bounds__(256) void cvt_f32_f16(const float* __restrict__ src,
                                                   f16* __restrict__ dst, int n4) {
  int i = blockIdx.x * 256 + threadIdx.x;
  int st = gridDim.x * 256;
  for (; i < n4; i += st) {
    float4 v = ((const float4*)src)[i];
    f16x4 h = {(f16)v.x, (f16)v.y, (f16)v.z, (f16)v.w};
    ((f16x4*)dst)[i] = h;
  }
}

// merged convert: hs (2*2^20 f32x4) -> hsd, Wq/Wk/Wv -> wd concat, Wo -> wod
__global__ __launch_bounds__(256) void cvt5_f32_f16(
    const float* __restrict__ hs, const float* __restrict__ s0,
    const float* __restrict__ s1, const float* __restrict__ s2,
    const float* __restrict__ s3, f16* __restrict__ hsd, f16* __restrict__ wd,
    f16* __restrict__ wod, int n4) {
  int i = blockIdx.x * 256 + threadIdx.x;
  int st = gridDim.x * 256;
  for (; i < n4; i += st) {
    float4 v;
    f16x4 h;
    if (i < 2 * 1048576) {
      v = ((const float4*)hs)[i];
      h[0] = (f16)v.x; h[1] = (f16)v.y; h[2] = (f16)v.z; h[3] = (f16)v.w;
      ((f16x4*)hsd)[i] = h;
    } else {
      const int j = i - 2 * 1048576;
      const int r = j >> 20, jj = j & 1048575;
      const float* s = (r == 0) ? s0 : ((r == 1) ? s1 : ((r == 2) ? s2 : s3));
      v = ((const float4*)s)[jj];
      h[0] = (f16)v.x; h[1] = (f16)v.y; h[2] = (f16)v.z; h[3] = (f16)v.w;
      if (r < 3) ((f16x4*)wd)[j] = h;
      else ((f16x4*)wod)[jj] = h;
    }
  }
}

// ============================================================================
// 8-phase-style GEMM: C = A(4096x2048) * B^T, B row-major [N][2048].
// Tile BM=128 x BN=256, BK=64, 8 waves (2M x 4N), wave tile 64x64.
// Triple-buffered LDS, 2-ahead staging, counted vmcnt(6), XOR swizzle, setprio.
// ============================================================================
template <int MODE>
__global__ __launch_bounds__(512, 2) void gemm8(const f16* __restrict__ A,
                                                const f16* __restrict__ Bm,
                                                const float* __restrict__ bias1,
                                                const float* __restrict__ bias2,
                                                float* __restrict__ outF,
                                                f16* __restrict__ outQ,
                                                f16* __restrict__ outK,
                                                f16* __restrict__ outV) {
  __shared__ __align__(16) f16 smem[73728];  // 144 KiB -> 1 block/CU, 8 waves
  const int tid = threadIdx.x;
  const int w = tid >> 6, l = tid & 63;
  const int wr = w >> 2, wc = w & 3;  // 2M x 4N wave grid
  const int sl = l & 15, t4 = l >> 4;

  const int nbx = gridDim.x, nby = gridDim.y;
  const int flat = blockIdx.y * nbx + blockIdx.x;
  const int chunk = (nbx * nby) >> 3;
  const int swz = (flat & 7) * chunk + (flat >> 3);
  const int col0 = (swz / nby) * 256, row0 = (swz % nby) * 128;

  f32x4 acc[4][4] = {};

  const int sr8 = l >> 3;
  const int sch = (l & 7) ^ (sr8 & 7);
  const f16* gA0 = A + (size_t)(row0 + w * 8 + sr8) * DM + sch * 8;
  const f16* gB0 = Bm + (size_t)(col0 + w * 8 + sr8) * DM + sch * 8;

#define SA(tb, kt, r) \
  gload16(gA0 + (size_t)(r) * 64 * DM + (kt) * 64, smem + (tb) * 8192 + (r) * 4096 + w * 512)
#define SB(tb, kt, r)                               \
  gload16(gB0 + (size_t)(r) * 64 * DM + (kt) * 64, \
          smem + 24576 + (tb) * 16384 + (r) * 4096 + w * 512)
#define MF(mi, ni, av, bv) \
  acc[mi][ni] = __builtin_amdgcn_mfma_f32_16x16x32_f16(av, bv, acc[mi][ni], 0, 0, 0)

  const int sx = sl & 7;
  const int sk0 = (t4 ^ sx) * 8;
  const int sk1 = ((4 + t4) ^ sx) * 8;
  const int arow = (wr * 64 + sl) * 64;
  const int brow = (wc * 64 + sl) * 64;

  SA(0, 0, 0); SA(0, 0, 1);
  SB(0, 0, 0); SB(0, 0, 1); SB(0, 0, 2); SB(0, 0, 3);
  SA(1, 1, 0); SA(1, 1, 1);
  SB(1, 1, 0); SB(1, 1, 1); SB(1, 1, 2); SB(1, 1, 3);
  VMC6;
  __builtin_amdgcn_s_barrier();

  int cur = 0;
#pragma unroll 1
  for (int t = 0; t < 32; ++t) {
    const int nb = (cur == 0) ? 2 : cur - 1;
    const bool pf = (t + 2 < 32);
    const int ab = cur * 8192;
    const int bb = 24576 + cur * 16384;
    f16x8 b0, b1, b2, b3, a0, a1;

    b0 = *(const f16x8*)&smem[bb + brow + sk0];
    b1 = *(const f16x8*)&smem[bb + brow + 1024 + sk0];
    b2 = *(const f16x8*)&smem[bb + brow + 2048 + sk0];
    b3 = *(const f16x8*)&smem[bb + brow + 3072 + sk0];
    a0 = *(const f16x8*)&smem[ab + arow + sk0];
    a1 = *(const f16x8*)&smem[ab + arow + 1024 + sk0];
    if (pf) { SA(nb, t + 2, 0); SA(nb, t + 2, 1); }
    __builtin_amdgcn_s_barrier();
    LGKM0;
    __builtin_amdgcn_s_setprio(1);
    MF(0, 0, a0, b0); MF(0, 1, a0, b1); MF(0, 2, a0, b2); MF(0, 3, a0, b3);
    MF(1, 0, a1, b0); MF(1, 1, a1, b1); MF(1, 2, a1, b2); MF(1, 3, a1, b3);
    __builtin_amdgcn_s_setprio(0);
    __builtin_amdgcn_s_barrier();

    a0 = *(const f16x8*)&smem[ab + arow + 2048 + sk0];
    a1 = *(const f16x8*)&smem[ab + arow + 3072 + sk0];
    if (pf) { SB(nb, t + 2, 0); SB(nb, t + 2, 1); }
    __builtin_amdgcn_s_barrier();
    LGKM0;
    __builtin_amdgcn_s_setprio(1);
    MF(2, 0, a0, b0); MF(2, 1, a0, b1); MF(2, 2, a0, b2); MF(2, 3, a0, b3);
    MF(3, 0, a1, b0); MF(3, 1, a1, b1); MF(3, 2, a1, b2); MF(3, 3, a1, b3);
    __builtin_amdgcn_s_setprio(0);
    __builtin_amdgcn_s_barrier();

    b0 = *(const f16x8*)&smem[bb + brow + sk1];
    b1 = *(const f16x8*)&smem[bb + brow + 1024 + sk1];
    b2 = *(const f16x8*)&smem[bb + brow + 2048 + sk1];
    b3 = *(const f16x8*)&smem[bb + brow + 3072 + sk1];
    a0 = *(const f16x8*)&smem[ab + arow + sk1];
    a1 = *(const f16x8*)&smem[ab + arow + 1024 + sk1];
    if (pf) { SB(nb, t + 2, 2); SB(nb, t + 2, 3); }
    __builtin_amdgcn_s_barrier();
    LGKM0;
    __builtin_amdgcn_s_setprio(1);
    MF(0, 0, a0, b0); MF(0, 1, a0, b1); MF(0, 2, a0, b2); MF(0, 3, a0, b3);
    MF(1, 0, a1, b0); MF(1, 1, a1, b1); MF(1, 2, a1, b2); MF(1, 3, a1, b3);
    __builtin_amdgcn_s_setprio(0);
    __builtin_amdgcn_s_barrier();

    a0 = *(const f16x8*)&smem[ab + arow + 2048 + sk1];
    a1 = *(const f16x8*)&smem[ab + arow + 3072 + sk1];
    __builtin_amdgcn_s_barrier();
    LGKM0;
    __builtin_amdgcn_s_setprio(1);
    MF(2, 0, a0, b0); MF(2, 1, a0, b1); MF(2, 2, a0, b2); MF(2, 3, a0, b3);
    MF(3, 0, a1, b0); MF(3, 1, a1, b1); MF(3, 2, a1, b2); MF(3, 3, a1, b3);
    __builtin_amdgcn_s_setprio(0);
    if (t < 30) { VMC6; } else { VMC0; }
    __builtin_amdgcn_s_barrier();
    cur = (cur == 2) ? 0 : cur + 1;
  }
#undef SA
#undef SB
#undef MF

  const int rl0 = wr * 64 + t4 * 4;
  const int cl0 = wc * 64 + sl;
  if constexpr (MODE == 0) {
#pragma unroll
    for (int mi = 0; mi < 4; mi++) {
#pragma unroll
      for (int ni = 0; ni < 4; ni++) {
        const int col = col0 + cl0 + ni * 16;
        const float bi = bias1[col];
#pragma unroll
        for (int j = 0; j < 4; j++) {
          const int row = row0 + rl0 + mi * 16 + j;
          __builtin_nontemporal_store(acc[mi][ni][j] + bi, &outF[(size_t)row * DM + col]);
        }
      }
    }
  } else {
    const int region = col0 >> 11;
    const int c2 = col0 & 2047;
    __syncthreads();
    if (region == 2) {
#pragma unroll
      for (int mi = 0; mi < 4; mi++)
#pragma unroll
        for (int ni = 0; ni < 4; ni++) {
          const int cl = cl0 + ni * 16;
          const float bb2 = bias2[c2 + cl];
#pragma unroll
          for (int j = 0; j < 4; j++)
            smem[cl * 136 + rl0 + mi * 16 + j] = (f16)(acc[mi][ni][j] + bb2);
        }
      __syncthreads();
      const int b = row0 >> 11, s0 = row0 & 2047;
#pragma unroll
      for (int it = 0; it < 8; ++it) {
        const int ck = it * 512 + tid;
        const int ci = ck >> 4, cc = (ck & 15) * 8;
        const int dg = c2 + ci;
        *(f16x8*)&outV[((size_t)(b * 16 + (dg >> 7)) * HD + (dg & 127)) * SEQ + s0 + cc] =
            *(const f16x8*)&smem[ci * 136 + cc];
      }
    } else {
#pragma unroll
      for (int mi = 0; mi < 4; mi++)
#pragma unroll
        for (int ni = 0; ni < 4; ni++) {
          const int cl = cl0 + ni * 16;
          const int cg = c2 + cl;
          const float badd = (region == 0) ? bias1[cg] : 0.0f;
#pragma unroll
          for (int j = 0; j < 4; j++) {
            float v = acc[mi][ni][j] + badd;
            if (region == 0) v *= QSCALE;
            smem[(rl0 + mi * 16 + j) * 264 + cl] = (f16)v;
          }
        }
      __syncthreads();
      f16* const dst = (region == 0 ? outQ : outK) + (size_t)row0 * DM + c2;
#pragma unroll
      for (int it = 0; it < 8; ++it) {
        const int ck = it * 512 + tid;
        const int rr = ck >> 5, cc = (ck & 31) * 8;
        *(f16x8*)&dst[(size_t)rr * DM + cc] = *(const f16x8*)&smem[rr * 264 + cc];
      }
    }
  }
}

// ============================================================================
// Attention: one block = 64 q rows of one (b,h). BOTH passes key-sliced:
// wave w owns keys w*16..w*16+15 for ALL 64 q-rows; Q fragments for all 4
// row-groups loop-invariant in registers -> kf LDS reads 16 -> 4 per wave/iter.
// Pass 2: P fragments cross waves, so lP is double-buffered with one
// lgkmcnt(0)+s_barrier handoff per iter (no vmcnt drain - P stores in flight).
// PV stays row-owned (wave w computes rows w*16..+15). LDS 80 KiB, 2 blk/CU.
// ============================================================================
__global__ __launch_bounds__(256, 2) void attn(const f16* __restrict__ Q,
                                               const f16* __restrict__ Kt,
                                               const f16* __restrict__ Vt,
                                               float* __restrict__ Pout,
                                               f16* __restrict__ Oout) {
  __shared__ __align__(16) f16 smem[40960];  // 80 KiB -> 2 blocks/CU
  // pass 1: K ring bufs 0..3 @ (kb&3)*8192; Q staged @16384 (buf2);
  //         cross-wave partials @ f16-idx 32768 (as float[256])
  // pass 2: K @ (kb&1)*8192, V @ 16384+(kb&1)*8192, lP dbuf @ 32768+(kb&1)*4096
  const int tid = threadIdx.x, w = tid >> 6, l = tid & 63;
  const int t = l >> 4, sl = l & 15, t8 = l >> 3, sl8 = l & 7;

  // XCD swizzle: each XCD owns 4 whole (b,h) -> K/V L2-resident
  const int flat = blockIdx.y * gridDim.x + blockIdx.x;
  const int swz = (flat & 7) * 128 + (flat >> 3);
  const int bh = swz >> 5, q0 = (swz & 31) * 64;

  const int b = bh >> 4, h = bh & 15;
  const f16* Qg = Q + (size_t)(b * SEQ) * DM + h * HD;
  const f16* Kg = Kt + (size_t)(b * SEQ) * DM + h * HD;
  const f16* Vg = Vt + (size_t)bh * HD * SEQ;

  // ---- prologue: Q -> buf2, K0 -> buf0, K1 -> buf1
#pragma unroll
  for (int c = 0; c < 4; c++) {
    const int row = w * 16 + c * 4 + t;
    const int ch = sl ^ (row & 7);
    gload16(Qg + (size_t)(q0 + row) * DM + ch * 8, smem + 16384 + w * 2048 + c * 512);
    gload16(Kg + (size_t)row * DM + ch * 8, smem + w * 2048 + c * 512);
    gload16(Kg + (size_t)(64 + row) * DM + ch * 8, smem + 8192 + w * 2048 + c * 512);
  }
  __syncthreads();

  // Q fragments for ALL 4 row-groups (loop-invariant; row&7 == sl&7 for all u)
  f16x8 qfa[4][4];
#pragma unroll
  for (int u = 0; u < 4; u++) {
    const int row = u * 16 + sl;
#pragma unroll
    for (int g = 0; g < 4; g++) {
      const int ch = (g * 4 + t) ^ (row & 7);
      qfa[u][g] = *(const f16x8*)&smem[16384 + row * 128 + ch * 8];
    }
  }
  // all waves done reading Q from buf2 before pass-1 prefetch reuses it
  LGKM0;
  __builtin_amdgcn_s_barrier();

  // ---- pass 1: key-sliced. Lane holds S[key=w*16+t*4+j][qrow=u*16+sl].
  float lsum[4] = {0.f, 0.f, 0.f, 0.f};
  const int mykey = w * 16 + sl;  // key&7 == sl&7
#pragma unroll 1
  for (int kb = 0; kb < 32; ++kb) {
    f16* const kc = smem + (kb & 3) * 8192;
    if (kb + 2 < 32) {
      f16* const kn = smem + ((kb + 2) & 3) * 8192;
#pragma unroll
      for (int c = 0; c < 4; c++) {
        const int row = w * 16 + c * 4 + t;
        const int ch = sl ^ (row & 7);
        gload16(Kg + (size_t)((kb + 2) * 64 + row) * DM + ch * 8, kn + w * 2048 + c * 512);
      }
    }
    f16x8 kf[4];
#pragma unroll
    for (int g = 0; g < 4; ++g) {
      const int ch = (g * 4 + t) ^ (mykey & 7);
      kf[g] = *(const f16x8*)&kc[mykey * 128 + ch * 8];
    }
    __builtin_amdgcn_s_setprio(1);
#pragma unroll
    for (int u = 0; u < 4; ++u) {
      f32x4 s = {0.f, 0.f, 0.f, 0.f};
#pragma unroll
      for (int g = 0; g < 4; ++g)
        s = __builtin_amdgcn_mfma_f32_16x16x32_f16(kf[g], qfa[u][g], s, 0, 0, 0);
#pragma unroll
      for (int j = 0; j < 4; j++) lsum[u] += __builtin_amdgcn_exp2f(s[j]);
    }
    __builtin_amdgcn_s_setprio(0);
    if (kb < 31) {
      if (kb + 2 < 32) { VMC4; } else { VMC0; }
      __builtin_amdgcn_s_barrier();
    }
  }
#pragma unroll
  for (int u = 0; u < 4; u++) {
    lsum[u] += __shfl_xor(lsum[u], 16);
    lsum[u] += __shfl_xor(lsum[u], 32);
  }
  // cross-wave reduce via LDS partials
  float* const part = (float*)(smem + 32768);
  if (t == 0) {
#pragma unroll
    for (int u = 0; u < 4; u++) part[w * 64 + u * 16 + sl] = lsum[u];
  }
  __syncthreads();
  float inv4[4];
#pragma unroll
  for (int u = 0; u < 4; u++) {
    const int r = u * 16 + sl;
    inv4[u] = 1.0f / (part[r] + part[64 + r] + part[128 + r] + part[192 + r]);
  }
  const int qrow = w * 16 + sl;  // pass-2 PV row ownership

  // ---- pass 2 prologue: stage K0 + V0 (buf0 reads long since done)
  {
#pragma unroll
    for (int c = 0; c < 4; c++) {
      const int row = w * 16 + c * 4 + t;
      const int ch = sl ^ (row & 7);
      gload16(Kg + (size_t)row * DM + ch * 8, smem + w * 2048 + c * 512);
    }
#pragma unroll
    for (int c = 0; c < 4; c++) {
      const int row = w * 32 + c * 8 + t8;
      const int ch = sl8 ^ (row & 7);
      gload16(Vg + (size_t)row * SEQ + ch * 8, smem + 16384 + w * 2048 + c * 512);
    }
  }
  __syncthreads();  // drains lgkm (inv4 reads done in all waves) + vmcnt

  f32x4 oacc[8] = {};
  float* const Pbase = Pout + ((size_t)bh * SEQ + q0) * SEQ;

  // ---- pass 2: key-sliced QK, row-owned PV, lP dbuf handoff
#pragma unroll 1
  for (int kb = 0; kb < 32; ++kb) {
    f16* const kc = smem + (kb & 1) * 8192;
    f16* const vc = smem + 16384 + (kb & 1) * 8192;
    f16* const lPc = smem + 32768 + (kb & 1) * 4096;
    if (kb < 31) {  // loads issued FIRST (older than the P stores below)
      f16* const kn = smem + ((kb + 1) & 1) * 8192;
      f16* const vn = smem + 16384 + ((kb + 1) & 1) * 8192;
#pragma unroll
      for (int c = 0; c < 4; c++) {
        const int row = w * 16 + c * 4 + t;
        const int ch = sl ^ (row & 7);
        gload16(Kg + (size_t)((kb + 1) * 64 + row) * DM + ch * 8, kn + w * 2048 + c * 512);
      }
#pragma unroll
      for (int c = 0; c < 4; c++) {
        const int row = w * 32 + c * 8 + t8;
        const int ch = sl8 ^ (row & 7);
        gload16(Vg + (size_t)row * SEQ + (kb + 1) * 64 + ch * 8, vn + w * 2048 + c * 512);
      }
    }
    // QK (key-sliced): 4 kf reads feed 16 MFMAs across 4 row-groups
    f16x8 kf[4];
#pragma unroll
    for (int g = 0; g < 4; ++g) {
      const int ch = (g * 4 + t) ^ (mykey & 7);
      kf[g] = *(const f16x8*)&kc[mykey * 128 + ch * 8];
    }
#pragma unroll
    for (int u = 0; u < 4; ++u) {
      f32x4 s = {0.f, 0.f, 0.f, 0.f};
#pragma unroll
      for (int g = 0; g < 4; ++g)
        s = __builtin_amdgcn_mfma_f32_16x16x32_f16(kf[g], qfa[u][g], s, 0, 0, 0);
      f32x4 p4;
      f16x4 ph;
#pragma unroll
      for (int j = 0; j < 4; j++) {
        const float p = __builtin_amdgcn_exp2f(s[j]) * inv4[u];
        p4[j] = p;
        ph[j] = (f16)p;
      }
      // lane holds keys w*16+t*4.. of row u*16+sl
      __builtin_nontemporal_store(
          p4, (f32x4*)(Pbase + (size_t)(u * 16 + sl) * SEQ + kb * 64 + w * 16 + t * 4));
      const int chs = (w * 2 + (t >> 1)) ^ (sl & 7);
      *(f16x4*)&lPc[(u * 16 + sl) * 64 + chs * 8 + (t & 1) * 4] = ph;
    }
    // cross-wave lP handoff: LDS writes visible, P stores stay in flight
    LGKM0;
    __builtin_amdgcn_s_barrier();
    f16x8 pf[2];
#pragma unroll
    for (int ks = 0; ks < 2; ++ks) {
      const int ch = (ks * 4 + t) ^ (qrow & 7);
      pf[ks] = *(const f16x8*)&lPc[qrow * 64 + ch * 8];
    }
    __builtin_amdgcn_s_setprio(1);
#pragma unroll
    for (int cb = 0; cb < 8; ++cb) {
      const int d = cb * 16 + sl;
#pragma unroll
      for (int ks = 0; ks < 2; ++ks) {
        const int ch = (ks * 4 + t) ^ (d & 7);
        f16x8 vf = *(const f16x8*)&vc[d * 64 + ch * 8];
        oacc[cb] = __builtin_amdgcn_mfma_f32_16x16x32_f16(pf[ks], vf, oacc[cb], 0, 0, 0);
      }
    }
    __builtin_amdgcn_s_setprio(0);
    if (kb < 31) {
      VMC4;  // 8 loads (older) retired; <=4 P-stores may still be in flight
      __builtin_amdgcn_s_barrier();
    }
  }

  // O epilogue: [b,h,q,d] -> merged [n][2048] f16 for the final GEMM
#pragma unroll
  for (int cb = 0; cb < 8; ++cb) {
    const int d = cb * 16 + sl;
#pragma unroll
    for (int j = 0; j < 4; j++) {
      const int lrow = w * 16 + t * 4 + j;
      Oout[((size_t)(b * SEQ + q0 + lrow)) * DM + h * HD + d] = (f16)oacc[cb][j];
    }
  }
}

extern "C" void kernel_launch(void* const* d_in, const int* in_sizes, int n_in,
                              void* d_out, int out_size, void* d_ws, size_t ws_size,
                              hipStream_t stream) {
  const float* hs = (const float*)d_in[0];
  const float* Wq = (const float*)d_in[1];
  const float* bq = (const float*)d_in[2];
  const float* Wk = (const float*)d_in[3];
  const float* Wv = (const float*)d_in[4];
  const float* bv = (const float*)d_in[5];
  const float* Wo = (const float*)d_in[6];
  const float* bo = (const float*)d_in[7];
  float* out = (float*)d_out;
  float* Pout = out + (size_t)NT * DM;  // attn_weights region (134M f32)

  // d_ws: 4 x 16 MiB f16 buffers (+ optional 8 MiB Wo16 if ws allows)
  f16* q16 = (f16*)d_ws;
  f16* k16 = q16 + (size_t)NT * DM;
  f16* vt16 = k16 + (size_t)NT * DM;
  f16* ao16 = vt16 + (size_t)NT * DM;
  f16* hs16 = (f16*)Pout;  // scratch inside P region (overwritten by attn)
  f16* wqkv16 = hs16 + (size_t)NT * DM;  // [6144][2048] f16

  const bool bigws = ws_size >= (size_t)72 * 1024 * 1024 + 65536;
  f16* wo16 = bigws ? (ao16 + (size_t)NT * DM) : q16;

  cvt5_f32_f16<<<2048, 256, 0, stream>>>(hs, Wq, Wk, Wv, Wo, hs16, wqkv16, wo16,
                                         bigws ? 6 * 1048576 : 5 * 1048576);

  gemm8<3><<<dim3(6144 / 256, NT / 128), 512, 0, stream>>>(
      hs16, wqkv16, bq, bv, nullptr, q16, k16, vt16);

  attn<<<dim3(SEQ / 64, NBH), 256, 0, stream>>>(q16, k16, vt16, Pout, ao16);

  if (!bigws) cvt_f32_f16<<<1024, 256, 0, stream>>>(Wo, wo16, DM * DM / 4);
  gemm8<0><<<dim3(DM / 256, NT / 128), 512, 0, stream>>>(
      ao16, wo16, bo, nullptr, out, nullptr, nullptr, nullptr);
}

// Round 15
// 360.723 us; speedup vs baseline: 1.0902x; 1.0065x over previous
//
#include <hip/hip_runtime.h>

typedef _Float16 f16;
typedef _Float16 f16x4 __attribute__((ext_vector_type(4)));
typedef _Float16 f16x8 __attribute__((ext_vector_type(8)));
typedef float f32x4 __attribute__((ext_vector_type(4)));

#define DM 2048
#define NT 4096
#define SEQ 2048
#define HD 128
#define NBH 32
// 1/sqrt(128) * log2(e): scores come out in log2 domain -> exp2 is one v_exp_f32
#define QSCALE (0.08838834764831845f * 1.4426950408889634f)

__device__ __forceinline__ void gload16(const f16* g, f16* l) {
  __builtin_amdgcn_global_load_lds(
      (const __attribute__((address_space(1))) void*)g,
      (__attribute__((address_space(3))) void*)l, 16, 0, 0);
}

#define LGKM0                                        \
  asm volatile("s_waitcnt lgkmcnt(0)" ::: "memory"); \
  __builtin_amdgcn_sched_barrier(0)
#define VMC6                                       \
  asm volatile("s_waitcnt vmcnt(6)" ::: "memory"); \
  __builtin_amdgcn_sched_barrier(0)
#define VMC4                                       \
  asm volatile("s_waitcnt vmcnt(4)" ::: "memory"); \
  __builtin_amdgcn_sched_barrier(0)
#define VMC0                                       \
  asm volatile("s_waitcnt vmcnt(0)" ::: "memory"); \
  __builtin_amdgcn_sched_barrier(0)

__global__ __launch_bounds__(256) void cvt_f32_f16(const float* __restrict__ src,
                                                   f16* __restrict__ dst, int n4) {
  int i = blockIdx.x * 256 + threadIdx.x;
  int st = gridDim.x * 256;
  for (; i < n4; i += st) {
    float4 v = ((const float4*)src)[i];
    f16x4 h = {(f16)v.x, (f16)v.y, (f16)v.z, (f16)v.w};
    ((f16x4*)dst)[i] = h;
  }
}

// merged convert: hs (2*2^20 f32x4) -> hsd, Wq/Wk/Wv -> wd concat, Wo -> wod
__global__ __launch_bounds__(256) void cvt5_f32_f16(
    const float* __restrict__ hs, const float* __restrict__ s0,
    const float* __restrict__ s1, const float* __restrict__ s2,
    const float* __restrict__ s3, f16* __restrict__ hsd, f16* __restrict__ wd,
    f16* __restrict__ wod, int n4) {
  int i = blockIdx.x * 256 + threadIdx.x;
  int st = gridDim.x * 256;
  for (; i < n4; i += st) {
    float4 v;
    f16x4 h;
    if (i < 2 * 1048576) {
      v = ((const float4*)hs)[i];
      h[0] = (f16)v.x; h[1] = (f16)v.y; h[2] = (f16)v.z; h[3] = (f16)v.w;
      ((f16x4*)hsd)[i] = h;
    } else {
      const int j = i - 2 * 1048576;
      const int r = j >> 20, jj = j & 1048575;
      const float* s = (r == 0) ? s0 : ((r == 1) ? s1 : ((r == 2) ? s2 : s3));
      v = ((const float4*)s)[jj];
      h[0] = (f16)v.x; h[1] = (f16)v.y; h[2] = (f16)v.z; h[3] = (f16)v.w;
      if (r < 3) ((f16x4*)wd)[j] = h;
      else ((f16x4*)wod)[jj] = h;
    }
  }
}

// ============================================================================
// 8-phase-style GEMM: C = A(4096x2048) * B^T, B row-major [N][2048].
// Tile BM=128 x BN=256, BK=64, 8 waves (2M x 4N), wave tile 64x64.
// Triple-buffered LDS, 2-ahead staging, counted vmcnt(6), XOR swizzle, setprio.
// ============================================================================
template <int MODE>
__global__ __launch_bounds__(512, 2) void gemm8(const f16* __restrict__ A,
                                                const f16* __restrict__ Bm,
                                                const float* __restrict__ bias1,
                                                const float* __restrict__ bias2,
                                                float* __restrict__ outF,
                                                f16* __restrict__ outQ,
                                                f16* __restrict__ outK,
                                                f16* __restrict__ outV) {
  __shared__ __align__(16) f16 smem[73728];  // 144 KiB -> 1 block/CU, 8 waves
  const int tid = threadIdx.x;
  const int w = tid >> 6, l = tid & 63;
  const int wr = w >> 2, wc = w & 3;  // 2M x 4N wave grid
  const int sl = l & 15, t4 = l >> 4;

  const int nbx = gridDim.x, nby = gridDim.y;
  const int flat = blockIdx.y * nbx + blockIdx.x;
  const int chunk = (nbx * nby) >> 3;
  const int swz = (flat & 7) * chunk + (flat >> 3);
  const int col0 = (swz / nby) * 256, row0 = (swz % nby) * 128;

  f32x4 acc[4][4] = {};

  const int sr8 = l >> 3;
  const int sch = (l & 7) ^ (sr8 & 7);
  const f16* gA0 = A + (size_t)(row0 + w * 8 + sr8) * DM + sch * 8;
  const f16* gB0 = Bm + (size_t)(col0 + w * 8 + sr8) * DM + sch * 8;

#define SA(tb, kt, r) \
  gload16(gA0 + (size_t)(r) * 64 * DM + (kt) * 64, smem + (tb) * 8192 + (r) * 4096 + w * 512)
#define SB(tb, kt, r)                               \
  gload16(gB0 + (size_t)(r) * 64 * DM + (kt) * 64, \
          smem + 24576 + (tb) * 16384 + (r) * 4096 + w * 512)
#define MF(mi, ni, av, bv) \
  acc[mi][ni] = __builtin_amdgcn_mfma_f32_16x16x32_f16(av, bv, acc[mi][ni], 0, 0, 0)

  const int sx = sl & 7;
  const int sk0 = (t4 ^ sx) * 8;
  const int sk1 = ((4 + t4) ^ sx) * 8;
  const int arow = (wr * 64 + sl) * 64;
  const int brow = (wc * 64 + sl) * 64;

  SA(0, 0, 0); SA(0, 0, 1);
  SB(0, 0, 0); SB(0, 0, 1); SB(0, 0, 2); SB(0, 0, 3);
  SA(1, 1, 0); SA(1, 1, 1);
  SB(1, 1, 0); SB(1, 1, 1); SB(1, 1, 2); SB(1, 1, 3);
  VMC6;
  __builtin_amdgcn_s_barrier();

  int cur = 0;
#pragma unroll 1
  for (int t = 0; t < 32; ++t) {
    const int nb = (cur == 0) ? 2 : cur - 1;
    const bool pf = (t + 2 < 32);
    const int ab = cur * 8192;
    const int bb = 24576 + cur * 16384;
    f16x8 b0, b1, b2, b3, a0, a1;

    b0 = *(const f16x8*)&smem[bb + brow + sk0];
    b1 = *(const f16x8*)&smem[bb + brow + 1024 + sk0];
    b2 = *(const f16x8*)&smem[bb + brow + 2048 + sk0];
    b3 = *(const f16x8*)&smem[bb + brow + 3072 + sk0];
    a0 = *(const f16x8*)&smem[ab + arow + sk0];
    a1 = *(const f16x8*)&smem[ab + arow + 1024 + sk0];
    if (pf) { SA(nb, t + 2, 0); SA(nb, t + 2, 1); }
    __builtin_amdgcn_s_barrier();
    LGKM0;
    __builtin_amdgcn_s_setprio(1);
    MF(0, 0, a0, b0); MF(0, 1, a0, b1); MF(0, 2, a0, b2); MF(0, 3, a0, b3);
    MF(1, 0, a1, b0); MF(1, 1, a1, b1); MF(1, 2, a1, b2); MF(1, 3, a1, b3);
    __builtin_amdgcn_s_setprio(0);
    __builtin_amdgcn_s_barrier();

    a0 = *(const f16x8*)&smem[ab + arow + 2048 + sk0];
    a1 = *(const f16x8*)&smem[ab + arow + 3072 + sk0];
    if (pf) { SB(nb, t + 2, 0); SB(nb, t + 2, 1); }
    __builtin_amdgcn_s_barrier();
    LGKM0;
    __builtin_amdgcn_s_setprio(1);
    MF(2, 0, a0, b0); MF(2, 1, a0, b1); MF(2, 2, a0, b2); MF(2, 3, a0, b3);
    MF(3, 0, a1, b0); MF(3, 1, a1, b1); MF(3, 2, a1, b2); MF(3, 3, a1, b3);
    __builtin_amdgcn_s_setprio(0);
    __builtin_amdgcn_s_barrier();

    b0 = *(const f16x8*)&smem[bb + brow + sk1];
    b1 = *(const f16x8*)&smem[bb + brow + 1024 + sk1];
    b2 = *(const f16x8*)&smem[bb + brow + 2048 + sk1];
    b3 = *(const f16x8*)&smem[bb + brow + 3072 + sk1];
    a0 = *(const f16x8*)&smem[ab + arow + sk1];
    a1 = *(const f16x8*)&smem[ab + arow + 1024 + sk1];
    if (pf) { SB(nb, t + 2, 2); SB(nb, t + 2, 3); }
    __builtin_amdgcn_s_barrier();
    LGKM0;
    __builtin_amdgcn_s_setprio(1);
    MF(0, 0, a0, b0); MF(0, 1, a0, b1); MF(0, 2, a0, b2); MF(0, 3, a0, b3);
    MF(1, 0, a1, b0); MF(1, 1, a1, b1); MF(1, 2, a1, b2); MF(1, 3, a1, b3);
    __builtin_amdgcn_s_setprio(0);
    __builtin_amdgcn_s_barrier();

    a0 = *(const f16x8*)&smem[ab + arow + 2048 + sk1];
    a1 = *(const f16x8*)&smem[ab + arow + 3072 + sk1];
    __builtin_amdgcn_s_barrier();
    LGKM0;
    __builtin_amdgcn_s_setprio(1);
    MF(2, 0, a0, b0); MF(2, 1, a0, b1); MF(2, 2, a0, b2); MF(2, 3, a0, b3);
    MF(3, 0, a1, b0); MF(3, 1, a1, b1); MF(3, 2, a1, b2); MF(3, 3, a1, b3);
    __builtin_amdgcn_s_setprio(0);
    if (t < 30) { VMC6; } else { VMC0; }
    __builtin_amdgcn_s_barrier();
    cur = (cur == 2) ? 0 : cur + 1;
  }
#undef SA
#undef SB
#undef MF

  const int rl0 = wr * 64 + t4 * 4;
  const int cl0 = wc * 64 + sl;
  if constexpr (MODE == 0) {
#pragma unroll
    for (int mi = 0; mi < 4; mi++) {
#pragma unroll
      for (int ni = 0; ni < 4; ni++) {
        const int col = col0 + cl0 + ni * 16;
        const float bi = bias1[col];
#pragma unroll
        for (int j = 0; j < 4; j++) {
          const int row = row0 + rl0 + mi * 16 + j;
          __builtin_nontemporal_store(acc[mi][ni][j] + bi, &outF[(size_t)row * DM + col]);
        }
      }
    }
  } else {
    const int region = col0 >> 11;
    const int c2 = col0 & 2047;
    __syncthreads();
    if (region == 2) {
#pragma unroll
      for (int mi = 0; mi < 4; mi++)
#pragma unroll
        for (int ni = 0; ni < 4; ni++) {
          const int cl = cl0 + ni * 16;
          const float bb2 = bias2[c2 + cl];
#pragma unroll
          for (int j = 0; j < 4; j++)
            smem[cl * 136 + rl0 + mi * 16 + j] = (f16)(acc[mi][ni][j] + bb2);
        }
      __syncthreads();
      const int b = row0 >> 11, s0 = row0 & 2047;
#pragma unroll
      for (int it = 0; it < 8; ++it) {
        const int ck = it * 512 + tid;
        const int ci = ck >> 4, cc = (ck & 15) * 8;
        const int dg = c2 + ci;
        *(f16x8*)&outV[((size_t)(b * 16 + (dg >> 7)) * HD + (dg & 127)) * SEQ + s0 + cc] =
            *(const f16x8*)&smem[ci * 136 + cc];
      }
    } else {
#pragma unroll
      for (int mi = 0; mi < 4; mi++)
#pragma unroll
        for (int ni = 0; ni < 4; ni++) {
          const int cl = cl0 + ni * 16;
          const int cg = c2 + cl;
          const float badd = (region == 0) ? bias1[cg] : 0.0f;
#pragma unroll
          for (int j = 0; j < 4; j++) {
            float v = acc[mi][ni][j] + badd;
            if (region == 0) v *= QSCALE;
            smem[(rl0 + mi * 16 + j) * 264 + cl] = (f16)v;
          }
        }
      __syncthreads();
      f16* const dst = (region == 0 ? outQ : outK) + (size_t)row0 * DM + c2;
#pragma unroll
      for (int it = 0; it < 8; ++it) {
        const int ck = it * 512 + tid;
        const int rr = ck >> 5, cc = (ck & 31) * 8;
        *(f16x8*)&dst[(size_t)rr * DM + cc] = *(const f16x8*)&smem[rr * 264 + cc];
      }
    }
  }
}

// ============================================================================
// Attention: one block = 64 q rows of one (b,h). BOTH passes key-sliced QK
// (wave w owns keys w*16..+15 for ALL 64 q-rows; Q frags loop-invariant ->
// kf reads 16->4/wave/iter) AND d-sliced PV (wave w owns d-blocks w*2,w*2+1
// for ALL 4 row-groups -> vf reads 16->4, pf 2->8; net LDS reads 22->16).
// lP double-buffered; one lgkmcnt(0)+s_barrier handoff per iter (no vmcnt
// drain - P stores stay in flight). LDS 80 KiB, 2 blk/CU.
// ============================================================================
__global__ __launch_bounds__(256, 2) void attn(const f16* __restrict__ Q,
                                               const f16* __restrict__ Kt,
                                               const f16* __restrict__ Vt,
                                               float* __restrict__ Pout,
                                               f16* __restrict__ Oout) {
  __shared__ __align__(16) f16 smem[40960];  // 80 KiB -> 2 blocks/CU
  // pass 1: K ring bufs 0..3 @ (kb&3)*8192; Q staged @16384 (buf2);
  //         cross-wave partials @ f16-idx 32768 (as float[256])
  // pass 2: K @ (kb&1)*8192, V @ 16384+(kb&1)*8192, lP dbuf @ 32768+(kb&1)*4096
  const int tid = threadIdx.x, w = tid >> 6, l = tid & 63;
  const int t = l >> 4, sl = l & 15, t8 = l >> 3, sl8 = l & 7;

  // XCD swizzle: each XCD owns 4 whole (b,h) -> K/V L2-resident
  const int flat = blockIdx.y * gridDim.x + blockIdx.x;
  const int swz = (flat & 7) * 128 + (flat >> 3);
  const int bh = swz >> 5, q0 = (swz & 31) * 64;

  const int b = bh >> 4, h = bh & 15;
  const f16* Qg = Q + (size_t)(b * SEQ) * DM + h * HD;
  const f16* Kg = Kt + (size_t)(b * SEQ) * DM + h * HD;
  const f16* Vg = Vt + (size_t)bh * HD * SEQ;

  // ---- prologue: Q -> buf2, K0 -> buf0, K1 -> buf1
#pragma unroll
  for (int c = 0; c < 4; c++) {
    const int row = w * 16 + c * 4 + t;
    const int ch = sl ^ (row & 7);
    gload16(Qg + (size_t)(q0 + row) * DM + ch * 8, smem + 16384 + w * 2048 + c * 512);
    gload16(Kg + (size_t)row * DM + ch * 8, smem + w * 2048 + c * 512);
    gload16(Kg + (size_t)(64 + row) * DM + ch * 8, smem + 8192 + w * 2048 + c * 512);
  }
  __syncthreads();

  // Q fragments for ALL 4 row-groups (loop-invariant; row&7 == sl&7 for all u)
  f16x8 qfa[4][4];
#pragma unroll
  for (int u = 0; u < 4; u++) {
    const int row = u * 16 + sl;
#pragma unroll
    for (int g = 0; g < 4; g++) {
      const int ch = (g * 4 + t) ^ (row & 7);
      qfa[u][g] = *(const f16x8*)&smem[16384 + row * 128 + ch * 8];
    }
  }
  // all waves done reading Q from buf2 before pass-1 prefetch reuses it
  LGKM0;
  __builtin_amdgcn_s_barrier();

  // ---- pass 1: key-sliced. Lane holds S[key=w*16+t*4+j][qrow=u*16+sl].
  float lsum[4] = {0.f, 0.f, 0.f, 0.f};
  const int mykey = w * 16 + sl;  // key&7 == sl&7
#pragma unroll 1
  for (int kb = 0; kb < 32; ++kb) {
    f16* const kc = smem + (kb & 3) * 8192;
    if (kb + 2 < 32) {
      f16* const kn = smem + ((kb + 2) & 3) * 8192;
#pragma unroll
      for (int c = 0; c < 4; c++) {
        const int row = w * 16 + c * 4 + t;
        const int ch = sl ^ (row & 7);
        gload16(Kg + (size_t)((kb + 2) * 64 + row) * DM + ch * 8, kn + w * 2048 + c * 512);
      }
    }
    f16x8 kf[4];
#pragma unroll
    for (int g = 0; g < 4; ++g) {
      const int ch = (g * 4 + t) ^ (mykey & 7);
      kf[g] = *(const f16x8*)&kc[mykey * 128 + ch * 8];
    }
    __builtin_amdgcn_s_setprio(1);
#pragma unroll
    for (int u = 0; u < 4; ++u) {
      f32x4 s = {0.f, 0.f, 0.f, 0.f};
#pragma unroll
      for (int g = 0; g < 4; ++g)
        s = __builtin_amdgcn_mfma_f32_16x16x32_f16(kf[g], qfa[u][g], s, 0, 0, 0);
#pragma unroll
      for (int j = 0; j < 4; j++) lsum[u] += __builtin_amdgcn_exp2f(s[j]);
    }
    __builtin_amdgcn_s_setprio(0);
    if (kb < 31) {
      if (kb + 2 < 32) { VMC4; } else { VMC0; }
      __builtin_amdgcn_s_barrier();
    }
  }
#pragma unroll
  for (int u = 0; u < 4; u++) {
    lsum[u] += __shfl_xor(lsum[u], 16);
    lsum[u] += __shfl_xor(lsum[u], 32);
  }
  // cross-wave reduce via LDS partials
  float* const part = (float*)(smem + 32768);
  if (t == 0) {
#pragma unroll
    for (int u = 0; u < 4; u++) part[w * 64 + u * 16 + sl] = lsum[u];
  }
  __syncthreads();
  float inv4[4];
#pragma unroll
  for (int u = 0; u < 4; u++) {
    const int r = u * 16 + sl;
    inv4[u] = 1.0f / (part[r] + part[64 + r] + part[128 + r] + part[192 + r]);
  }

  // ---- pass 2 prologue: stage K0 + V0 (buf0 reads long since done)
  {
#pragma unroll
    for (int c = 0; c < 4; c++) {
      const int row = w * 16 + c * 4 + t;
      const int ch = sl ^ (row & 7);
      gload16(Kg + (size_t)row * DM + ch * 8, smem + w * 2048 + c * 512);
    }
#pragma unroll
    for (int c = 0; c < 4; c++) {
      const int row = w * 32 + c * 8 + t8;
      const int ch = sl8 ^ (row & 7);
      gload16(Vg + (size_t)row * SEQ + ch * 8, smem + 16384 + w * 2048 + c * 512);
    }
  }
  __syncthreads();  // drains lgkm (inv4 reads done in all waves) + vmcnt

  f32x4 oacc[4][2] = {};  // [row-group u][my d-block dd]
  float* const Pbase = Pout + ((size_t)bh * SEQ + q0) * SEQ;

  // ---- pass 2: key-sliced QK, d-sliced PV, lP dbuf handoff
#pragma unroll 1
  for (int kb = 0; kb < 32; ++kb) {
    f16* const kc = smem + (kb & 1) * 8192;
    f16* const vc = smem + 16384 + (kb & 1) * 8192;
    f16* const lPc = smem + 32768 + (kb & 1) * 4096;
    if (kb < 31) {  // loads issued FIRST (older than the P stores below)
      f16* const kn = smem + ((kb + 1) & 1) * 8192;
      f16* const vn = smem + 16384 + ((kb + 1) & 1) * 8192;
#pragma unroll
      for (int c = 0; c < 4; c++) {
        const int row = w * 16 + c * 4 + t;
        const int ch = sl ^ (row & 7);
        gload16(Kg + (size_t)((kb + 1) * 64 + row) * DM + ch * 8, kn + w * 2048 + c * 512);
      }
#pragma unroll
      for (int c = 0; c < 4; c++) {
        const int row = w * 32 + c * 8 + t8;
        const int ch = sl8 ^ (row & 7);
        gload16(Vg + (size_t)row * SEQ + (kb + 1) * 64 + ch * 8, vn + w * 2048 + c * 512);
      }
    }
    // QK (key-sliced): 4 kf reads feed 16 MFMAs across 4 row-groups
    f16x8 kf[4];
#pragma unroll
    for (int g = 0; g < 4; ++g) {
      const int ch = (g * 4 + t) ^ (mykey & 7);
      kf[g] = *(const f16x8*)&kc[mykey * 128 + ch * 8];
    }
#pragma unroll
    for (int u = 0; u < 4; ++u) {
      f32x4 s = {0.f, 0.f, 0.f, 0.f};
#pragma unroll
      for (int g = 0; g < 4; ++g)
        s = __builtin_amdgcn_mfma_f32_16x16x32_f16(kf[g], qfa[u][g], s, 0, 0, 0);
      f32x4 p4;
      f16x4 ph;
#pragma unroll
      for (int j = 0; j < 4; j++) {
        const float p = __builtin_amdgcn_exp2f(s[j]) * inv4[u];
        p4[j] = p;
        ph[j] = (f16)p;
      }
      // lane holds keys w*16+t*4.. of row u*16+sl
      __builtin_nontemporal_store(
          p4, (f32x4*)(Pbase + (size_t)(u * 16 + sl) * SEQ + kb * 64 + w * 16 + t * 4));
      const int chs = (w * 2 + (t >> 1)) ^ (sl & 7);
      *(f16x4*)&lPc[(u * 16 + sl) * 64 + chs * 8 + (t & 1) * 4] = ph;
    }
    // cross-wave lP handoff: LDS writes visible, P stores stay in flight
    LGKM0;
    __builtin_amdgcn_s_barrier();
    // PV (d-sliced): pf for all 4 row-groups (8 reads) + vf for my 2 d-blocks (4)
    f16x8 pfa[4][2];
#pragma unroll
    for (int u = 0; u < 4; ++u)
#pragma unroll
      for (int ks = 0; ks < 2; ++ks) {
        const int ch = (ks * 4 + t) ^ (sl & 7);
        pfa[u][ks] = *(const f16x8*)&lPc[(u * 16 + sl) * 64 + ch * 8];
      }
    __builtin_amdgcn_s_setprio(1);
#pragma unroll
    for (int dd = 0; dd < 2; ++dd) {
      const int d = (w * 2 + dd) * 16 + sl;
      f16x8 vf0 = *(const f16x8*)&vc[d * 64 + ((t ^ (d & 7)) * 8)];
      f16x8 vf1 = *(const f16x8*)&vc[d * 64 + (((4 + t) ^ (d & 7)) * 8)];
#pragma unroll
      for (int u = 0; u < 4; ++u) {
        oacc[u][dd] = __builtin_amdgcn_mfma_f32_16x16x32_f16(pfa[u][0], vf0, oacc[u][dd], 0, 0, 0);
        oacc[u][dd] = __builtin_amdgcn_mfma_f32_16x16x32_f16(pfa[u][1], vf1, oacc[u][dd], 0, 0, 0);
      }
    }
    __builtin_amdgcn_s_setprio(0);
    if (kb < 31) {
      VMC4;  // 8 loads (older) retired; <=4 P-stores may still be in flight
      __builtin_amdgcn_s_barrier();
    }
  }

  // O epilogue: [b,h,q,d] -> merged [n][2048] f16 for the final GEMM
#pragma unroll
  for (int u = 0; u < 4; ++u) {
#pragma unroll
    for (int dd = 0; dd < 2; ++dd) {
      const int d = (w * 2 + dd) * 16 + sl;
#pragma unroll
      for (int j = 0; j < 4; j++) {
        const int lrow = u * 16 + t * 4 + j;
        Oout[((size_t)(b * SEQ + q0 + lrow)) * DM + h * HD + d] = (f16)oacc[u][dd][j];
      }
    }
  }
}

extern "C" void kernel_launch(void* const* d_in, const int* in_sizes, int n_in,
                              void* d_out, int out_size, void* d_ws, size_t ws_size,
                              hipStream_t stream) {
  const float* hs = (const float*)d_in[0];
  const float* Wq = (const float*)d_in[1];
  const float* bq = (const float*)d_in[2];
  const float* Wk = (const float*)d_in[3];
  const float* Wv = (const float*)d_in[4];
  const float* bv = (const float*)d_in[5];
  const float* Wo = (const float*)d_in[6];
  const float* bo = (const float*)d_in[7];
  float* out = (float*)d_out;
  float* Pout = out + (size_t)NT * DM;  // attn_weights region (134M f32)

  // d_ws: 4 x 16 MiB f16 buffers (+ optional 8 MiB Wo16 if ws allows)
  f16* q16 = (f16*)d_ws;
  f16* k16 = q16 + (size_t)NT * DM;
  f16* vt16 = k16 + (size_t)NT * DM;
  f16* ao16 = vt16 + (size_t)NT * DM;
  f16* hs16 = (f16*)Pout;  // scratch inside P region (overwritten by attn)
  f16* wqkv16 = hs16 + (size_t)NT * DM;  // [6144][2048] f16

  const bool bigws = ws_size >= (size_t)72 * 1024 * 1024 + 65536;
  f16* wo16 = bigws ? (ao16 + (size_t)NT * DM) : q16;

  cvt5_f32_f16<<<2048, 256, 0, stream>>>(hs, Wq, Wk, Wv, Wo, hs16, wqkv16, wo16,
                                         bigws ? 6 * 1048576 : 5 * 1048576);

  gemm8<3><<<dim3(6144 / 256, NT / 128), 512, 0, stream>>>(
      hs16, wqkv16, bq, bv, nullptr, q16, k16, vt16);

  attn<<<dim3(SEQ / 64, NBH), 256, 0, stream>>>(q16, k16, vt16, Pout, ao16);

  if (!bigws) cvt_f32_f16<<<1024, 256, 0, stream>>>(Wo, wo16, DM * DM / 4);
  gemm8<0><<<dim3(DM / 256, NT / 128), 512, 0, stream>>>(
      ao16, wo16, bo, nullptr, out, nullptr, nullptr, nullptr);
}